// Round 1
// baseline (2330.516 us; speedup 1.0000x reference)
//
#include <hip/hip_runtime.h>
#include <hip/hip_bf16.h>
#include <math.h>

// Problem constants
// B=4, NQ=300, NC=16, C=256, NH=8, NP=4, DFF=2048, H=W=128
// Lq = 4800, head dim = 32

__device__ __forceinline__ float wave_sum(float v) {
#pragma unroll
    for (int o = 32; o; o >>= 1) v += __shfl_xor(v, o);
    return v;
}
__device__ __forceinline__ float wave_max(float v) {
#pragma unroll
    for (int o = 32; o; o >>= 1) v = fmaxf(v, __shfl_xor(v, o));
    return v;
}

// mean/var over 256 elements, block = 256 threads (4 waves)
__device__ __forceinline__ void block_meanvar(float v, float* sb, float& mean, float& rstd) {
    float s = v, s2 = v * v;
#pragma unroll
    for (int o = 32; o; o >>= 1) { s += __shfl_xor(s, o); s2 += __shfl_xor(s2, o); }
    int wv = threadIdx.x >> 6;
    if ((threadIdx.x & 63) == 0) { sb[wv] = s; sb[4 + wv] = s2; }
    __syncthreads();
    s  = sb[0] + sb[1] + sb[2] + sb[3];
    s2 = sb[4] + sb[5] + sb[6] + sb[7];
    mean = s * (1.f / 256.f);
    float var = s2 * (1.f / 256.f) - mean * mean;
    rstd = 1.f / sqrtf(var + 1e-5f);
    __syncthreads();
}

// ---------------------------------------------------------------------------
// Generic fp32 GEMM: C[M,N] = A[M,K] @ W[N,K]^T + bias[N]   (both K-contiguous)
// tile 64x64, KT=32, 256 threads, 4x4 acc per thread. relu flag fuses max(0,.)
// ---------------------------------------------------------------------------
__global__ __launch_bounds__(256) void gemm_nt(
    const float* __restrict__ A, const float* __restrict__ W,
    const float* __restrict__ bias, float* __restrict__ C,
    int M, int N, int K, int relu)
{
    __shared__ float As[64][33];
    __shared__ float Ws[64][33];
    const int bm = blockIdx.y << 6, bn = blockIdx.x << 6;
    const int tid = threadIdx.x;
    const int tx = tid & 15, ty = tid >> 4;
    float acc[4][4] = {};
    for (int k0 = 0; k0 < K; k0 += 32) {
#pragma unroll
        for (int s = 0; s < 2; ++s) {
            int item = tid + s * 256;           // 0..511
            int row = item >> 3, kv = (item & 7) << 2;
            int gr = bm + row;
            float4 v = make_float4(0.f, 0.f, 0.f, 0.f);
            if (gr < M) v = *(const float4*)(A + (size_t)gr * K + k0 + kv);
            As[row][kv + 0] = v.x; As[row][kv + 1] = v.y;
            As[row][kv + 2] = v.z; As[row][kv + 3] = v.w;
            int gn = bn + row;
            float4 u = make_float4(0.f, 0.f, 0.f, 0.f);
            if (gn < N) u = *(const float4*)(W + (size_t)gn * K + k0 + kv);
            Ws[row][kv + 0] = u.x; Ws[row][kv + 1] = u.y;
            Ws[row][kv + 2] = u.z; Ws[row][kv + 3] = u.w;
        }
        __syncthreads();
#pragma unroll
        for (int kk = 0; kk < 32; ++kk) {
            float a0 = As[ty * 4 + 0][kk], a1 = As[ty * 4 + 1][kk];
            float a2 = As[ty * 4 + 2][kk], a3 = As[ty * 4 + 3][kk];
            float w0 = Ws[tx * 4 + 0][kk], w1 = Ws[tx * 4 + 1][kk];
            float w2 = Ws[tx * 4 + 2][kk], w3 = Ws[tx * 4 + 3][kk];
            acc[0][0] += a0 * w0; acc[0][1] += a0 * w1; acc[0][2] += a0 * w2; acc[0][3] += a0 * w3;
            acc[1][0] += a1 * w0; acc[1][1] += a1 * w1; acc[1][2] += a1 * w2; acc[1][3] += a1 * w3;
            acc[2][0] += a2 * w0; acc[2][1] += a2 * w1; acc[2][2] += a2 * w2; acc[2][3] += a2 * w3;
            acc[3][0] += a3 * w0; acc[3][1] += a3 * w1; acc[3][2] += a3 * w2; acc[3][3] += a3 * w3;
        }
        __syncthreads();
    }
#pragma unroll
    for (int i = 0; i < 4; ++i) {
        int gr = bm + ty * 4 + i;
        if (gr >= M) continue;
#pragma unroll
        for (int j = 0; j < 4; ++j) {
            int gn = bn + tx * 4 + j;
            if (gn >= N) continue;
            float v = acc[i][j] + bias[gn];
            if (relu) v = fmaxf(v, 0.f);
            C[(size_t)gr * N + gn] = v;
        }
    }
}

// ---------------------------------------------------------------------------
// MHA over packed qkv[M=BI*300][768]; q cols h*32.., k at 256+h*32, v at 512+h*32
// one block per (batch-item, head); K,V staged in LDS as bf16; one wave per query.
// Output written row-major O[bi*300+q][256] at col h*32+d.
// ---------------------------------------------------------------------------
__global__ __launch_bounds__(256) void attn_kernel(
    const float* __restrict__ qkv, float* __restrict__ O, int BI)
{
    const int bh = blockIdx.x;
    const int bi = bh >> 3, h = bh & 7;
    __shared__ __hip_bfloat16 Ks[300][34];
    __shared__ __hip_bfloat16 Vs[300][34];
    __shared__ float pbuf[4][304];
    const int tid = threadIdx.x;
    for (int idx = tid; idx < 300 * 32; idx += 256) {
        int k = idx >> 5, d = idx & 31;
        const float* base = qkv + ((size_t)(bi * 300 + k)) * 768 + h * 32 + d;
        Ks[k][d] = __float2bfloat16(base[256]);
        Vs[k][d] = __float2bfloat16(base[512]);
    }
    __syncthreads();
    const int wave = tid >> 6, lane = tid & 63;
    const int dd = lane & 31, half = lane >> 5;
    const float scale = 0.17677669529663687f;  // 1/sqrt(32)
    for (int q = wave; q < 300; q += 4) {
        float qv[32];
        const float* qp = qkv + ((size_t)(bi * 300 + q)) * 768 + h * 32;
#pragma unroll
        for (int d4 = 0; d4 < 8; ++d4) {
            float4 t = *(const float4*)(qp + d4 * 4);
            qv[d4 * 4 + 0] = t.x; qv[d4 * 4 + 1] = t.y;
            qv[d4 * 4 + 2] = t.z; qv[d4 * 4 + 3] = t.w;
        }
        float s[5];
        float m = -1e30f;
#pragma unroll
        for (int j = 0; j < 5; ++j) {
            int k = lane + 64 * j;
            float a = -1e30f;
            if (k < 300) {
                a = 0.f;
#pragma unroll
                for (int d = 0; d < 32; ++d) a += qv[d] * __bfloat162float(Ks[k][d]);
                a *= scale;
            }
            s[j] = a;
            m = fmaxf(m, a);
        }
        m = wave_max(m);
        float lsum = 0.f;
#pragma unroll
        for (int j = 0; j < 5; ++j) { s[j] = expf(s[j] - m); lsum += s[j]; }
        lsum = wave_sum(lsum);
        float rinv = 1.f / lsum;
#pragma unroll
        for (int j = 0; j < 5; ++j) {
            int k = lane + 64 * j;
            if (k < 300) pbuf[wave][k] = s[j] * rinv;
        }
        // same-wave LDS write->read; fence to be safe
        asm volatile("s_waitcnt lgkmcnt(0)" ::: "memory");
        float acc = 0.f;
        const int k0 = half * 150;
        for (int k = k0; k < k0 + 150; ++k)
            acc += pbuf[wave][k] * __bfloat162float(Vs[k][dd]);
        acc += __shfl_xor(acc, 32);
        if (half == 0) O[((size_t)(bi * 300 + q)) * 256 + h * 32 + dd] = acc;
    }
}

// sc_x[(b*16+nc)*300+nq][c] = sub_contour_query[b][nq][nc][c]
__global__ __launch_bounds__(256) void sc_transpose(
    const float* __restrict__ scq, float* __restrict__ out)
{
    int row = blockIdx.x;              // output row
    int b = row / 4800;
    int rem = row % 4800;
    int nc = rem / 300, nq = rem % 300;
    int c = threadIdx.x;
    out[(size_t)row * 256 + c] = scq[((size_t)((b * 300 + nq) * 16 + nc)) * 256 + c];
}

// tgt = LN( scq + 2*(sc_o + inst_o) ) with n1
__global__ __launch_bounds__(256) void ln1_combine(
    const float* __restrict__ scq, const float* __restrict__ sco,
    const float* __restrict__ insto, const float* __restrict__ g,
    const float* __restrict__ bta, float* __restrict__ tgt)
{
    __shared__ float sb[8];
    int row = blockIdx.x;              // b*4800 + nq*16 + nc
    int b = row / 4800;
    int rem = row % 4800;
    int nq = rem >> 4, nc = rem & 15;
    int c = threadIdx.x;
    float v = scq[(size_t)row * 256 + c]
            + 2.f * (sco[((size_t)((b * 16 + nc) * 300 + nq)) * 256 + c]
                   + insto[((size_t)(b * 300 + nq)) * 256 + c]);
    float mean, rstd;
    block_meanvar(v, sb, mean, rstd);
    tgt[(size_t)row * 256 + c] = (v - mean) * rstd * g[c] + bta[c];
}

// dst = LN(x + y)
__global__ __launch_bounds__(256) void ln_add(
    const float* __restrict__ x, const float* __restrict__ y,
    const float* __restrict__ g, const float* __restrict__ bta,
    float* __restrict__ dst)
{
    __shared__ float sb[8];
    int row = blockIdx.x;
    int c = threadIdx.x;
    float v = x[(size_t)row * 256 + c] + y[(size_t)row * 256 + c];
    float mean, rstd;
    block_meanvar(v, sb, mean, rstd);
    dst[(size_t)row * 256 + c] = (v - mean) * rstd * g[c] + bta[c];
}

// deformable bilinear sampling + attention-weight reduce over NP=4
// one block per (b,lq); thread = channel (h = tid>>5, d = tid&31)
__global__ __launch_bounds__(256) void deform_sample(
    const float* __restrict__ offb, const float* __restrict__ awb,
    const float* __restrict__ refb, const float* __restrict__ mem,
    const int* __restrict__ Hp, const int* __restrict__ Wp,
    float* __restrict__ samp)
{
    const int row = blockIdx.x;        // b*4800 + lq
    const int b = row / 4800;
    const int tid = threadIdx.x;
    const int h = tid >> 5;
    const int H = *Hp, Wd = *Wp;
    const float4 rb = *(const float4*)(refb + (size_t)row * 4);
    const float* awp = awb + (size_t)row * 32 + h * 4;
    float a0 = awp[0], a1 = awp[1], a2 = awp[2], a3 = awp[3];
    float am = fmaxf(fmaxf(a0, a1), fmaxf(a2, a3));
    float e0 = expf(a0 - am), e1 = expf(a1 - am), e2 = expf(a2 - am), e3 = expf(a3 - am);
    float rs = 1.f / (e0 + e1 + e2 + e3);
    float wp[4] = { e0 * rs, e1 * rs, e2 * rs, e3 * rs };
    const float* op = offb + (size_t)row * 64 + h * 8;
    const float* mb = mem + (size_t)b * H * Wd * 256 + tid;   // channel = tid
    float acc = 0.f;
#pragma unroll
    for (int p = 0; p < 4; ++p) {
        float ox = op[p * 2 + 0], oy = op[p * 2 + 1];
        float lx = rb.x + ox * rb.z * 0.5f;
        float ly = rb.y + oy * rb.w * 0.5f;
        float gx = lx * (float)Wd - 0.5f;
        float gy = ly * (float)H - 0.5f;
        float x0f = floorf(gx), y0f = floorf(gy);
        int x0 = (int)x0f, y0 = (int)y0f;
        float wx1 = gx - x0f, wy1 = gy - y0f;
        float wx0 = 1.f - wx1, wy0 = 1.f - wy1;
        float v = 0.f;
#pragma unroll
        for (int cy = 0; cy < 2; ++cy) {
            int yi = y0 + cy;
            if ((unsigned)yi >= (unsigned)H) continue;
            float wy = cy ? wy1 : wy0;
#pragma unroll
            for (int cx = 0; cx < 2; ++cx) {
                int xi = x0 + cx;
                if ((unsigned)xi >= (unsigned)Wd) continue;
                float wx = cx ? wx1 : wx0;
                v += wx * wy * mb[(size_t)(yi * Wd + xi) * 256];
            }
        }
        acc += wp[p] * v;
    }
    samp[(size_t)row * 256 + tid] = acc;
}

extern "C" void kernel_launch(void* const* d_in, const int* in_sizes, int n_in,
                              void* d_out, int out_size, void* d_ws, size_t ws_size,
                              hipStream_t stream) {
    const float* inst_query = (const float*)d_in[0];
    const float* sub_contour = (const float*)d_in[1];
    const float* memory_feats = (const float*)d_in[2];
    const float* ref_boxes = (const float*)d_in[3];
    const float* inst_in_w = (const float*)d_in[4];
    const float* inst_in_b = (const float*)d_in[5];
    const float* inst_out_w = (const float*)d_in[6];
    const float* inst_out_b = (const float*)d_in[7];
    const float* sc_in_w = (const float*)d_in[8];
    const float* sc_in_b = (const float*)d_in[9];
    const float* sc_out_w = (const float*)d_in[10];
    const float* sc_out_b = (const float*)d_in[11];
    const float* off_w = (const float*)d_in[12];
    const float* off_b = (const float*)d_in[13];
    const float* aw_w = (const float*)d_in[14];
    const float* aw_b = (const float*)d_in[15];
    const float* outp_w = (const float*)d_in[16];
    const float* outp_b = (const float*)d_in[17];
    const float* lin1_w = (const float*)d_in[18];
    const float* lin1_b = (const float*)d_in[19];
    const float* lin2_w = (const float*)d_in[20];
    const float* lin2_b = (const float*)d_in[21];
    const float* n1_g = (const float*)d_in[22];
    const float* n1_b = (const float*)d_in[23];
    const float* n2_g = (const float*)d_in[24];
    const float* n2_b = (const float*)d_in[25];
    const float* n3_g = (const float*)d_in[26];
    const float* n3_b = (const float*)d_in[27];
    const int* Hp = (const int*)d_in[28];
    const int* Wp = (const int*)d_in[29];

    float* ws = (float*)d_ws;
    float* qkv   = ws;                      // 19200*768 = 14,745,600
    float* xbuf  = qkv + 14745600;          // 19200*256 = 4,915,200
    float* obuf  = xbuf + 4915200;          // 19200*256
    float* insto = obuf + 4915200;          // 1200*256 = 307,200
    float* tgt   = insto + 307200;          // 19200*256
    float* t2    = tgt + 4915200;           // 19200*256
    float* offb  = t2 + 4915200;            // 19200*64 = 1,228,800
    float* awb   = offb + 1228800;          // 19200*32 = 614,400
    float* ffn1  = qkv;                     // alias: 4800*2048 = 9,830,400 < qkv size

    dim3 blk(256);

    // 1. inst QKV: (1200,256)@(768,256)^T
    gemm_nt<<<dim3(12, 19), blk, 0, stream>>>(inst_query, inst_in_w, inst_in_b, qkv, 1200, 768, 256, 0);
    // 2. inst attention (4 batch items x 8 heads)
    attn_kernel<<<32, blk, 0, stream>>>(qkv, obuf, 4);
    // 3. inst out-proj -> inst_o
    gemm_nt<<<dim3(4, 19), blk, 0, stream>>>(obuf, inst_out_w, inst_out_b, insto, 1200, 256, 256, 0);
    // 4. sc transpose -> xbuf (sc row order)
    sc_transpose<<<19200, blk, 0, stream>>>(sub_contour, xbuf);
    // 5. sc QKV
    gemm_nt<<<dim3(12, 300), blk, 0, stream>>>(xbuf, sc_in_w, sc_in_b, qkv, 19200, 768, 256, 0);
    // 6. sc attention (64 batch items x 8 heads)
    attn_kernel<<<512, blk, 0, stream>>>(qkv, obuf, 64);
    // 7. sc out-proj -> t2 (= sc_o rows, sc order)
    gemm_nt<<<dim3(4, 300), blk, 0, stream>>>(obuf, sc_out_w, sc_out_b, t2, 19200, 256, 256, 0);
    // 8. combine + LN1 -> tgt
    ln1_combine<<<19200, blk, 0, stream>>>(sub_contour, t2, insto, n1_g, n1_b, tgt);
    // 9. offsets / attention-weights projections
    gemm_nt<<<dim3(1, 300), blk, 0, stream>>>(tgt, off_w, off_b, offb, 19200, 64, 256, 0);
    gemm_nt<<<dim3(1, 300), blk, 0, stream>>>(tgt, aw_w, aw_b, awb, 19200, 32, 256, 0);
    // 10. deformable sampling -> obuf (reused as samp_av)
    deform_sample<<<19200, blk, 0, stream>>>(offb, awb, ref_boxes, memory_feats, Hp, Wp, obuf);
    // 11. outp proj -> t2
    gemm_nt<<<dim3(4, 300), blk, 0, stream>>>(obuf, outp_w, outp_b, t2, 19200, 256, 256, 0);
    // 12. LN2 (in-place on tgt)
    ln_add<<<19200, blk, 0, stream>>>(tgt, t2, n2_g, n2_b, tgt);
    // 13. FFN in 4 row-chunks (ffn1 aliases dead qkv buffer)
    for (int c = 0; c < 4; ++c) {
        const float* a = tgt + (size_t)c * 4800 * 256;
        gemm_nt<<<dim3(32, 75), blk, 0, stream>>>(a, lin1_w, lin1_b, ffn1, 4800, 2048, 256, 1);
        gemm_nt<<<dim3(4, 75), blk, 0, stream>>>(ffn1, lin2_w, lin2_b, t2 + (size_t)c * 4800 * 256, 4800, 256, 2048, 0);
    }
    // 14. LN3 -> output (B, NQ, NC, C) flat == tgt row layout
    ln_add<<<19200, blk, 0, stream>>>(tgt, t2, n3_g, n3_b, (float*)d_out);
}

// Round 2
// 704.535 us; speedup vs baseline: 3.3079x; 3.3079x over previous
//
#include <hip/hip_runtime.h>
#include <hip/hip_bf16.h>
#include <math.h>

// B=4, NQ=300, NC=16, C=256, NH=8, NP=4, DFF=2048, H=W=128, Lq=4800, hd=32

typedef unsigned short u16;
typedef unsigned int u32;
typedef __attribute__((ext_vector_type(4))) float f32x4;
typedef __attribute__((ext_vector_type(8))) short s16x8;

__device__ __forceinline__ float b2f(u16 u) {
    union { u32 u; float f; } v; v.u = ((u32)u) << 16; return v.f;
}
__device__ __forceinline__ u16 f2b(float f) {
    union { float f; u32 u; } v; v.f = f;
    u32 r = v.u + 0x7fffu + ((v.u >> 16) & 1u);
    return (u16)(r >> 16);
}

__device__ __forceinline__ float wave_sum(float v) {
#pragma unroll
    for (int o = 32; o; o >>= 1) v += __shfl_xor(v, o);
    return v;
}
__device__ __forceinline__ float wave_max(float v) {
#pragma unroll
    for (int o = 32; o; o >>= 1) v = fmaxf(v, __shfl_xor(v, o));
    return v;
}

// mean/var over 256 elements, block = 256 threads (4 waves)
__device__ __forceinline__ void block_meanvar(float v, float* sb, float& mean, float& rstd) {
    float s = v, s2 = v * v;
#pragma unroll
    for (int o = 32; o; o >>= 1) { s += __shfl_xor(s, o); s2 += __shfl_xor(s2, o); }
    int wv = threadIdx.x >> 6;
    if ((threadIdx.x & 63) == 0) { sb[wv] = s; sb[4 + wv] = s2; }
    __syncthreads();
    s  = sb[0] + sb[1] + sb[2] + sb[3];
    s2 = sb[4] + sb[5] + sb[6] + sb[7];
    mean = s * (1.f / 256.f);
    float var = s2 * (1.f / 256.f) - mean * mean;
    rstd = 1.f / sqrtf(var + 1e-5f);
    __syncthreads();
}

#define GLOAD_LDS16(g, l) \
    __builtin_amdgcn_global_load_lds((const __attribute__((address_space(1))) void*)(g), \
                                     (__attribute__((address_space(3))) void*)(l), 16, 0, 0)

// ---------------------------------------------------------------------------
// fp32 -> bf16 convert, 8 elems/thread, n multiple of 2048
// ---------------------------------------------------------------------------
__global__ __launch_bounds__(256) void cvt_bf16(const float* __restrict__ in,
                                                u16* __restrict__ out, int n) {
    int i = (blockIdx.x * 256 + threadIdx.x) * 8;
    if (i >= n) return;
    float4 a = *(const float4*)(in + i);
    float4 b = *(const float4*)(in + i + 4);
    u16 u[8] = { f2b(a.x), f2b(a.y), f2b(a.z), f2b(a.w),
                 f2b(b.x), f2b(b.y), f2b(b.z), f2b(b.w) };
    *(uint4*)(out + i) = *(const uint4*)u;
}

// ---------------------------------------------------------------------------
// MFMA bf16 GEMM: C[M,N] = A[M,K] @ W[N,K]^T + bias (m97-style 128x128, BK=32)
// N must be multiple of 128, K multiple of 32; M guarded.
// ---------------------------------------------------------------------------
template<int RELU, int OUTBF16>
__global__ __launch_bounds__(256) void gemm_mfma(
    const u16* __restrict__ A, const u16* __restrict__ W,
    const float* __restrict__ bias, void* __restrict__ Cout,
    int M, int N, int K)
{
    __shared__ u16 Asm[128 * 32];
    __shared__ u16 Bsm[128 * 32];
    const int tid = threadIdx.x;
    const int wave = tid >> 6, lane = tid & 63;
    const int bm = blockIdx.y * 128, bn = blockIdx.x * 128;
    const int wr = (wave >> 1) * 64, wc = (wave & 1) * 64;
    const int fr = lane & 15;            // fragment row within 16
    const int fk = (lane >> 4) * 8;      // k offset
    f32x4 acc[4][4] = {};

    for (int k0 = 0; k0 < K; k0 += 32) {
        __syncthreads();
#pragma unroll
        for (int c = 0; c < 2; ++c) {
            int chunk = wave + c * 4;                // 0..7
            int b = chunk * 1024 + lane * 16;        // byte within 8KB tile
            int row = b >> 6;                        // 64B per row (32 bf16)
            int ke = (b & 63) >> 1;                  // elem offset in row
            int ra = bm + row; if (ra >= M) ra = M - 1;
            GLOAD_LDS16(A + (size_t)ra * K + k0 + ke, Asm + chunk * 512);
            int rb = bn + row;
            GLOAD_LDS16(W + (size_t)rb * K + k0 + ke, Bsm + chunk * 512);
        }
        __syncthreads();
        s16x8 af[4], bf[4];
#pragma unroll
        for (int i = 0; i < 4; ++i) {
            af[i] = *(const s16x8*)(Asm + (wr + i * 16 + fr) * 32 + fk);
            bf[i] = *(const s16x8*)(Bsm + (wc + i * 16 + fr) * 32 + fk);
        }
#pragma unroll
        for (int mi = 0; mi < 4; ++mi)
#pragma unroll
            for (int ni = 0; ni < 4; ++ni)
                acc[mi][ni] = __builtin_amdgcn_mfma_f32_16x16x32_bf16(
                    af[mi], bf[ni], acc[mi][ni], 0, 0, 0);
    }
    // C/D layout: col = lane&15, row = (lane>>4)*4 + j   [m89/m91 verified]
    const int cc = lane & 15, cr4 = (lane >> 4) * 4;
#pragma unroll
    for (int mi = 0; mi < 4; ++mi) {
#pragma unroll
        for (int ni = 0; ni < 4; ++ni) {
            int col = bn + wc + ni * 16 + cc;
            float bv = bias[col];
#pragma unroll
            for (int j = 0; j < 4; ++j) {
                int row = bm + wr + mi * 16 + cr4 + j;
                if (row >= M) continue;
                float v = acc[mi][ni][j] + bv;
                if (RELU) v = fmaxf(v, 0.f);
                if (OUTBF16) ((u16*)Cout)[(size_t)row * N + col] = f2b(v);
                else ((float*)Cout)[(size_t)row * N + col] = v;
            }
        }
    }
}

// ---------------------------------------------------------------------------
// fp32 GEMM (kept for small-N off/aw projections): C = A @ W^T + bias
// ---------------------------------------------------------------------------
__global__ __launch_bounds__(256) void gemm_nt(
    const float* __restrict__ A, const float* __restrict__ W,
    const float* __restrict__ bias, float* __restrict__ C,
    int M, int N, int K, int relu)
{
    __shared__ float As[64][33];
    __shared__ float Ws[64][33];
    const int bm = blockIdx.y << 6, bn = blockIdx.x << 6;
    const int tid = threadIdx.x;
    const int tx = tid & 15, ty = tid >> 4;
    float acc[4][4] = {};
    for (int k0 = 0; k0 < K; k0 += 32) {
#pragma unroll
        for (int s = 0; s < 2; ++s) {
            int item = tid + s * 256;
            int row = item >> 3, kv = (item & 7) << 2;
            int gr = bm + row;
            float4 v = make_float4(0.f, 0.f, 0.f, 0.f);
            if (gr < M) v = *(const float4*)(A + (size_t)gr * K + k0 + kv);
            As[row][kv + 0] = v.x; As[row][kv + 1] = v.y;
            As[row][kv + 2] = v.z; As[row][kv + 3] = v.w;
            int gn = bn + row;
            float4 u = make_float4(0.f, 0.f, 0.f, 0.f);
            if (gn < N) u = *(const float4*)(W + (size_t)gn * K + k0 + kv);
            Ws[row][kv + 0] = u.x; Ws[row][kv + 1] = u.y;
            Ws[row][kv + 2] = u.z; Ws[row][kv + 3] = u.w;
        }
        __syncthreads();
#pragma unroll
        for (int kk = 0; kk < 32; ++kk) {
            float a0 = As[ty * 4 + 0][kk], a1 = As[ty * 4 + 1][kk];
            float a2 = As[ty * 4 + 2][kk], a3 = As[ty * 4 + 3][kk];
            float w0 = Ws[tx * 4 + 0][kk], w1 = Ws[tx * 4 + 1][kk];
            float w2 = Ws[tx * 4 + 2][kk], w3 = Ws[tx * 4 + 3][kk];
            acc[0][0] += a0 * w0; acc[0][1] += a0 * w1; acc[0][2] += a0 * w2; acc[0][3] += a0 * w3;
            acc[1][0] += a1 * w0; acc[1][1] += a1 * w1; acc[1][2] += a1 * w2; acc[1][3] += a1 * w3;
            acc[2][0] += a2 * w0; acc[2][1] += a2 * w1; acc[2][2] += a2 * w2; acc[2][3] += a2 * w3;
            acc[3][0] += a3 * w0; acc[3][1] += a3 * w1; acc[3][2] += a3 * w2; acc[3][3] += a3 * w3;
        }
        __syncthreads();
    }
#pragma unroll
    for (int i = 0; i < 4; ++i) {
        int gr = bm + ty * 4 + i;
        if (gr >= M) continue;
#pragma unroll
        for (int j = 0; j < 4; ++j) {
            int gn = bn + tx * 4 + j;
            if (gn >= N) continue;
            float v = acc[i][j] + bias[gn];
            if (relu) v = fmaxf(v, 0.f);
            C[(size_t)gr * N + gn] = v;
        }
    }
}

// ---------------------------------------------------------------------------
// MHA over packed bf16 qkv[BI*300][768]; block = (bi,h,seg); S segments/head.
// K row-major LDS [300][40] (80B stride), V transposed LDS [32][312].
// ---------------------------------------------------------------------------
__global__ __launch_bounds__(256) void attn_kernel(
    const u16* __restrict__ qkv, u16* __restrict__ O, int S)
{
    const int bh = blockIdx.x / S, seg = blockIdx.x % S;
    const int bi = bh >> 3, h = bh & 7;
    __shared__ u16 Ks[300][40];
    __shared__ u16 Vt[32][312];
    __shared__ float pbuf[4][304];
    const int tid = threadIdx.x;
    // stage K (vector) and V (transpose scatter)
    for (int idx = tid; idx < 1200; idx += 256) {
        int k = idx >> 2, sub = idx & 3;
        const u16* kp = qkv + ((size_t)(bi * 300 + k)) * 768 + 256 + h * 32 + sub * 8;
        *(uint4*)&Ks[k][sub * 8] = *(const uint4*)kp;
        u16 tmp[8];
        *(uint4*)tmp = *(const uint4*)(kp + 256);
#pragma unroll
        for (int j = 0; j < 8; ++j) Vt[sub * 8 + j][k] = tmp[j];
    }
    // zero tails so padded PV reads contribute 0 (avoid stale-NaN * 0)
    for (int idx = tid; idx < 384; idx += 256) Vt[idx / 12][300 + idx % 12] = 0;
    if (tid < 16) pbuf[tid >> 2][300 + (tid & 3)] = 0.f;
    __syncthreads();

    const int wave = tid >> 6, lane = tid & 63;
    const int dd = lane & 31, half = lane >> 5;
    const float scale = 0.17677669529663687f;  // 1/sqrt(32)
    for (int q = seg * 4 + wave; q < 300; q += 4 * S) {
        float qv[32];
        const u16* qp = qkv + ((size_t)(bi * 300 + q)) * 768 + h * 32;
#pragma unroll
        for (int sub = 0; sub < 4; ++sub) {
            uint4 u = *(const uint4*)(qp + sub * 8);
            u32 ua[4] = { u.x, u.y, u.z, u.w };
#pragma unroll
            for (int t = 0; t < 4; ++t) {
                qv[sub * 8 + t * 2]     = __uint_as_float(ua[t] << 16);
                qv[sub * 8 + t * 2 + 1] = __uint_as_float(ua[t] & 0xffff0000u);
            }
        }
        float s[5];
        float m = -1e30f;
#pragma unroll
        for (int j = 0; j < 5; ++j) {
            int k = lane + 64 * j;
            float a = -1e30f;
            if (k < 300) {
                float acc = 0.f;
#pragma unroll
                for (int sub = 0; sub < 4; ++sub) {
                    uint4 u = *(const uint4*)&Ks[k][sub * 8];
                    u32 ua[4] = { u.x, u.y, u.z, u.w };
#pragma unroll
                    for (int t = 0; t < 4; ++t) {
                        acc = fmaf(__uint_as_float(ua[t] << 16),        qv[sub * 8 + t * 2],     acc);
                        acc = fmaf(__uint_as_float(ua[t] & 0xffff0000u), qv[sub * 8 + t * 2 + 1], acc);
                    }
                }
                a = acc * scale;
            }
            s[j] = a;
            m = fmaxf(m, a);
        }
        m = wave_max(m);
        float lsum = 0.f;
#pragma unroll
        for (int j = 0; j < 5; ++j) { s[j] = __expf(s[j] - m); lsum += s[j]; }
        lsum = wave_sum(lsum);
        float rinv = 1.f / lsum;
#pragma unroll
        for (int j = 0; j < 5; ++j) {
            int k = lane + 64 * j;
            if (k < 300) pbuf[wave][k] = s[j] * rinv;
        }
        asm volatile("s_waitcnt lgkmcnt(0)" ::: "memory");
        // PV: lane (dd, half); half covers k in [half*152, half*152+152)
        float acc = 0.f;
        const int kb0 = half * 152;
#pragma unroll
        for (int i = 0; i < 19; ++i) {
            int kk = kb0 + i * 8;
            uint4 vv = *(const uint4*)&Vt[dd][kk];
            float4 p0 = *(const float4*)&pbuf[wave][kk];
            float4 p1 = *(const float4*)&pbuf[wave][kk + 4];
            u32 va[4] = { vv.x, vv.y, vv.z, vv.w };
            acc = fmaf(__uint_as_float(va[0] << 16),         p0.x, acc);
            acc = fmaf(__uint_as_float(va[0] & 0xffff0000u), p0.y, acc);
            acc = fmaf(__uint_as_float(va[1] << 16),         p0.z, acc);
            acc = fmaf(__uint_as_float(va[1] & 0xffff0000u), p0.w, acc);
            acc = fmaf(__uint_as_float(va[2] << 16),         p1.x, acc);
            acc = fmaf(__uint_as_float(va[2] & 0xffff0000u), p1.y, acc);
            acc = fmaf(__uint_as_float(va[3] << 16),         p1.z, acc);
            acc = fmaf(__uint_as_float(va[3] & 0xffff0000u), p1.w, acc);
        }
        acc += __shfl_xor(acc, 32);
        if (half == 0) O[((size_t)(bi * 300 + q)) * 256 + h * 32 + dd] = f2b(acc);
    }
}

// sc_x[(b*16+nc)*300+nq][c] = sub_contour_query[b][nq][nc][c]  (bf16 out)
__global__ __launch_bounds__(256) void sc_transpose(
    const float* __restrict__ scq, u16* __restrict__ out)
{
    int row = blockIdx.x;
    int b = row / 4800;
    int rem = row % 4800;
    int nc = rem / 300, nq = rem % 300;
    int c = threadIdx.x;
    out[(size_t)row * 256 + c] = f2b(scq[((size_t)((b * 300 + nq) * 16 + nc)) * 256 + c]);
}

// tgt = LN( scq + 2*(sc_o + inst_o) ) with n1
__global__ __launch_bounds__(256) void ln1_combine(
    const float* __restrict__ scq, const float* __restrict__ sco,
    const float* __restrict__ insto, const float* __restrict__ g,
    const float* __restrict__ bta, float* __restrict__ tgt)
{
    __shared__ float sb[8];
    int row = blockIdx.x;
    int b = row / 4800;
    int rem = row % 4800;
    int nq = rem >> 4, nc = rem & 15;
    int c = threadIdx.x;
    float v = scq[(size_t)row * 256 + c]
            + 2.f * (sco[((size_t)((b * 16 + nc) * 300 + nq)) * 256 + c]
                   + insto[((size_t)(b * 300 + nq)) * 256 + c]);
    float mean, rstd;
    block_meanvar(v, sb, mean, rstd);
    tgt[(size_t)row * 256 + c] = (v - mean) * rstd * g[c] + bta[c];
}

// dst = LN(x + y); optional bf16 copy
__global__ __launch_bounds__(256) void ln_add(
    const float* __restrict__ x, const float* __restrict__ y,
    const float* __restrict__ g, const float* __restrict__ bta,
    float* __restrict__ dst, u16* __restrict__ bdst)
{
    __shared__ float sb[8];
    int row = blockIdx.x;
    int c = threadIdx.x;
    float v = x[(size_t)row * 256 + c] + y[(size_t)row * 256 + c];
    float mean, rstd;
    block_meanvar(v, sb, mean, rstd);
    float r = (v - mean) * rstd * g[c] + bta[c];
    dst[(size_t)row * 256 + c] = r;
    if (bdst) bdst[(size_t)row * 256 + c] = f2b(r);
}

// deformable bilinear sampling + aw-softmax reduce over NP=4 (bf16 out)
__global__ __launch_bounds__(256) void deform_sample(
    const float* __restrict__ offb, const float* __restrict__ awb,
    const float* __restrict__ refb, const float* __restrict__ mem,
    const int* __restrict__ Hp, const int* __restrict__ Wp,
    u16* __restrict__ samp)
{
    const int row = blockIdx.x;
    const int b = row / 4800;
    const int tid = threadIdx.x;
    const int h = tid >> 5;
    const int H = *Hp, Wd = *Wp;
    const float4 rb = *(const float4*)(refb + (size_t)row * 4);
    const float* awp = awb + (size_t)row * 32 + h * 4;
    float a0 = awp[0], a1 = awp[1], a2 = awp[2], a3 = awp[3];
    float am = fmaxf(fmaxf(a0, a1), fmaxf(a2, a3));
    float e0 = __expf(a0 - am), e1 = __expf(a1 - am), e2 = __expf(a2 - am), e3 = __expf(a3 - am);
    float rs = 1.f / (e0 + e1 + e2 + e3);
    float wp[4] = { e0 * rs, e1 * rs, e2 * rs, e3 * rs };
    const float* op = offb + (size_t)row * 64 + h * 8;
    const float* mb = mem + (size_t)b * H * Wd * 256 + tid;
    float acc = 0.f;
#pragma unroll
    for (int p = 0; p < 4; ++p) {
        float ox = op[p * 2 + 0], oy = op[p * 2 + 1];
        float lx = rb.x + ox * rb.z * 0.5f;
        float ly = rb.y + oy * rb.w * 0.5f;
        float gx = lx * (float)Wd - 0.5f;
        float gy = ly * (float)H - 0.5f;
        float x0f = floorf(gx), y0f = floorf(gy);
        int x0 = (int)x0f, y0 = (int)y0f;
        float wx1 = gx - x0f, wy1 = gy - y0f;
        float wx0 = 1.f - wx1, wy0 = 1.f - wy1;
        float v = 0.f;
#pragma unroll
        for (int cy = 0; cy < 2; ++cy) {
            int yi = y0 + cy;
            if ((unsigned)yi >= (unsigned)H) continue;
            float wy = cy ? wy1 : wy0;
#pragma unroll
            for (int cx = 0; cx < 2; ++cx) {
                int xi = x0 + cx;
                if ((unsigned)xi >= (unsigned)Wd) continue;
                float wx = cx ? wx1 : wx0;
                v += wx * wy * mb[(size_t)(yi * Wd + xi) * 256];
            }
        }
        acc += wp[p] * v;
    }
    samp[(size_t)row * 256 + tid] = f2b(acc);
}

extern "C" void kernel_launch(void* const* d_in, const int* in_sizes, int n_in,
                              void* d_out, int out_size, void* d_ws, size_t ws_size,
                              hipStream_t stream) {
    const float* inst_query = (const float*)d_in[0];
    const float* sub_contour = (const float*)d_in[1];
    const float* memory_feats = (const float*)d_in[2];
    const float* ref_boxes = (const float*)d_in[3];
    const float* inst_in_w = (const float*)d_in[4];
    const float* inst_in_b = (const float*)d_in[5];
    const float* inst_out_w = (const float*)d_in[6];
    const float* inst_out_b = (const float*)d_in[7];
    const float* sc_in_w = (const float*)d_in[8];
    const float* sc_in_b = (const float*)d_in[9];
    const float* sc_out_w = (const float*)d_in[10];
    const float* sc_out_b = (const float*)d_in[11];
    const float* off_w = (const float*)d_in[12];
    const float* off_b = (const float*)d_in[13];
    const float* aw_w = (const float*)d_in[14];
    const float* aw_b = (const float*)d_in[15];
    const float* outp_w = (const float*)d_in[16];
    const float* outp_b = (const float*)d_in[17];
    const float* lin1_w = (const float*)d_in[18];
    const float* lin1_b = (const float*)d_in[19];
    const float* lin2_w = (const float*)d_in[20];
    const float* lin2_b = (const float*)d_in[21];
    const float* n1_g = (const float*)d_in[22];
    const float* n1_b = (const float*)d_in[23];
    const float* n2_g = (const float*)d_in[24];
    const float* n2_b = (const float*)d_in[25];
    const float* n3_g = (const float*)d_in[26];
    const float* n3_b = (const float*)d_in[27];
    const int* Hp = (const int*)d_in[28];
    const int* Wp = (const int*)d_in[29];

    // ---- workspace layout ----
    u16* wsb = (u16*)d_ws;
    u16* qkv_b   = wsb;                       // 19200*768  = 14,745,600
    u16* xbuf_b  = qkv_b + 14745600;          // 19200*256  =  4,915,200
    u16* obuf_b  = xbuf_b + 4915200;          //  4,915,200
    u16* tgt_b   = obuf_b + 4915200;          //  4,915,200
    u16* w_inst_in  = tgt_b + 4915200;        //    196,608
    u16* w_inst_out = w_inst_in + 196608;     //     65,536
    u16* w_sc_in    = w_inst_out + 65536;     //    196,608
    u16* w_sc_out   = w_sc_in + 196608;       //     65,536
    u16* w_outp     = w_sc_out + 65536;       //     65,536
    u16* w_lin1     = w_outp + 65536;         //    524,288
    u16* w_lin2     = w_lin1 + 524288;        //    524,288
    u16* ffn1_b = qkv_b;                      // alias qkv+xbuf = 19,660,800 elems
    u16* instq_b = tgt_b;                     // temp (tgt_b not live yet)
    float* fp    = (float*)(w_lin2 + 524288); // 16B-aligned
    float* insto = fp;                        //    307,200
    float* tgt   = insto + 307200;            //  4,915,200
    float* t2    = tgt + 4915200;             //  4,915,200
    float* offb  = t2 + 4915200;              //  1,228,800
    float* awb   = offb + 1228800;            //    614,400
    // total ~110.2 MB

    dim3 blk(256);

    // weight/activation conversions
    cvt_bf16<<<96,  blk, 0, stream>>>(inst_in_w,  w_inst_in,  196608);
    cvt_bf16<<<32,  blk, 0, stream>>>(inst_out_w, w_inst_out, 65536);
    cvt_bf16<<<96,  blk, 0, stream>>>(sc_in_w,    w_sc_in,    196608);
    cvt_bf16<<<32,  blk, 0, stream>>>(sc_out_w,   w_sc_out,   65536);
    cvt_bf16<<<32,  blk, 0, stream>>>(outp_w,     w_outp,     65536);
    cvt_bf16<<<256, blk, 0, stream>>>(lin1_w,     w_lin1,     524288);
    cvt_bf16<<<256, blk, 0, stream>>>(lin2_w,     w_lin2,     524288);
    cvt_bf16<<<150, blk, 0, stream>>>(inst_query, instq_b,    307200);

    // 1. inst QKV (1200x768x256) -> qkv_b (bf16)
    gemm_mfma<0,1><<<dim3(6, 10), blk, 0, stream>>>(instq_b, w_inst_in, inst_in_b, qkv_b, 1200, 768, 256);
    // 2. inst attention (4 bi x 8 h x S=4)
    attn_kernel<<<128, blk, 0, stream>>>(qkv_b, obuf_b, 4);
    // 3. inst out-proj -> insto (fp32)
    gemm_mfma<0,0><<<dim3(2, 10), blk, 0, stream>>>(obuf_b, w_inst_out, inst_out_b, insto, 1200, 256, 256);
    // 4. sc transpose -> xbuf_b (bf16)
    sc_transpose<<<19200, blk, 0, stream>>>(sub_contour, xbuf_b);
    // 5. sc QKV (19200x768x256) -> qkv_b
    gemm_mfma<0,1><<<dim3(6, 150), blk, 0, stream>>>(xbuf_b, w_sc_in, sc_in_b, qkv_b, 19200, 768, 256);
    // 6. sc attention (64 bi x 8 h x S=2)
    attn_kernel<<<1024, blk, 0, stream>>>(qkv_b, obuf_b, 2);
    // 7. sc out-proj -> t2 (fp32, sc row order)
    gemm_mfma<0,0><<<dim3(2, 150), blk, 0, stream>>>(obuf_b, w_sc_out, sc_out_b, t2, 19200, 256, 256);
    // 8. combine + LN1 -> tgt (fp32)
    ln1_combine<<<19200, blk, 0, stream>>>(sub_contour, t2, insto, n1_g, n1_b, tgt);
    // 9. offsets / attention-weights projections (fp32, small N)
    gemm_nt<<<dim3(1, 300), blk, 0, stream>>>(tgt, off_w, off_b, offb, 19200, 64, 256, 0);
    gemm_nt<<<dim3(1, 300), blk, 0, stream>>>(tgt, aw_w, aw_b, awb, 19200, 32, 256, 0);
    // 10. deformable sampling -> obuf_b (bf16)
    deform_sample<<<19200, blk, 0, stream>>>(offb, awb, ref_boxes, memory_feats, Hp, Wp, obuf_b);
    // 11. outp proj -> t2
    gemm_mfma<0,0><<<dim3(2, 150), blk, 0, stream>>>(obuf_b, w_outp, outp_b, t2, 19200, 256, 256);
    // 12. LN2 -> tgt (fp32) + tgt_b (bf16)
    ln_add<<<19200, blk, 0, stream>>>(tgt, t2, n2_g, n2_b, tgt, tgt_b);
    // 13. FFN in 2 chunks of 9600 rows (ffn1_b aliases dead qkv_b+xbuf_b)
    for (int c = 0; c < 2; ++c) {
        gemm_mfma<1,1><<<dim3(16, 75), blk, 0, stream>>>(tgt_b + (size_t)c * 9600 * 256, w_lin1, lin1_b, ffn1_b, 9600, 2048, 256);
        gemm_mfma<0,0><<<dim3(2, 75), blk, 0, stream>>>(ffn1_b, w_lin2, lin2_b, t2 + (size_t)c * 9600 * 256, 9600, 256, 2048);
    }
    // 14. LN3 -> output fp32 (B, NQ, NC, C)
    ln_add<<<19200, blk, 0, stream>>>(tgt, t2, n3_g, n3_b, (float*)d_out, nullptr);
}

// Round 3
// 522.455 us; speedup vs baseline: 4.4607x; 1.3485x over previous
//
#include <hip/hip_runtime.h>
#include <hip/hip_bf16.h>
#include <math.h>

// B=4, NQ=300, NC=16, C=256, NH=8, NP=4, DFF=2048, H=W=128, Lq=4800, hd=32

typedef unsigned short u16;
typedef unsigned int u32;
typedef __attribute__((ext_vector_type(4))) float f32x4;
typedef __attribute__((ext_vector_type(8))) short s16x8;

__device__ __forceinline__ float b2f(u16 u) {
    union { u32 u; float f; } v; v.u = ((u32)u) << 16; return v.f;
}
__device__ __forceinline__ u16 f2b(float f) {
    union { float f; u32 u; } v; v.f = f;
    u32 r = v.u + 0x7fffu + ((v.u >> 16) & 1u);
    return (u16)(r >> 16);
}

__device__ __forceinline__ float wave_sum(float v) {
#pragma unroll
    for (int o = 32; o; o >>= 1) v += __shfl_xor(v, o);
    return v;
}

// mean/var over 256 elements, block = 256 threads (4 waves)
__device__ __forceinline__ void block_meanvar(float v, float* sb, float& mean, float& rstd) {
    float s = v, s2 = v * v;
#pragma unroll
    for (int o = 32; o; o >>= 1) { s += __shfl_xor(s, o); s2 += __shfl_xor(s2, o); }
    int wv = threadIdx.x >> 6;
    if ((threadIdx.x & 63) == 0) { sb[wv] = s; sb[4 + wv] = s2; }
    __syncthreads();
    s  = sb[0] + sb[1] + sb[2] + sb[3];
    s2 = sb[4] + sb[5] + sb[6] + sb[7];
    mean = s * (1.f / 256.f);
    float var = s2 * (1.f / 256.f) - mean * mean;
    rstd = 1.f / sqrtf(var + 1e-5f);
    __syncthreads();
}

#define GLOAD_LDS16(g, l) \
    __builtin_amdgcn_global_load_lds((const __attribute__((address_space(1))) void*)(g), \
                                     (__attribute__((address_space(3))) void*)(l), 16, 0, 0)

// ---------------------------------------------------------------------------
// Fused fp32 -> bf16 conversion over up to 8 segments (all sizes % 8 == 0)
// ---------------------------------------------------------------------------
struct CvtSeg { const float* src; u16* dst; int nv; };  // nv = elems/8
struct Cvt8 { CvtSeg s[8]; };

__global__ __launch_bounds__(256) void cvt_multi(Cvt8 a, int totalv) {
    int v = blockIdx.x * 256 + threadIdx.x;
    if (v >= totalv) return;
    int si = 0;
    while (si < 7 && v >= a.s[si].nv) { v -= a.s[si].nv; ++si; }
    const float* src = a.s[si].src + (size_t)v * 8;
    u16* dst = a.s[si].dst + (size_t)v * 8;
    float4 x = *(const float4*)src;
    float4 y = *(const float4*)(src + 4);
    u16 u[8] = { f2b(x.x), f2b(x.y), f2b(x.z), f2b(x.w),
                 f2b(y.x), f2b(y.y), f2b(y.z), f2b(y.w) };
    *(uint4*)dst = *(const uint4*)u;
}

// ---------------------------------------------------------------------------
// MFMA bf16 GEMM: C[M,N] = A[M,K] @ W[N,K]^T + bias (128x128, BK=32)
// ---------------------------------------------------------------------------
template<int RELU, int OUTBF16>
__global__ __launch_bounds__(256) void gemm_mfma(
    const u16* __restrict__ A, const u16* __restrict__ W,
    const float* __restrict__ bias, void* __restrict__ Cout,
    int M, int N, int K)
{
    __shared__ u16 Asm[128 * 32];
    __shared__ u16 Bsm[128 * 32];
    const int tid = threadIdx.x;
    const int wave = tid >> 6, lane = tid & 63;
    const int bm = blockIdx.y * 128, bn = blockIdx.x * 128;
    const int wr = (wave >> 1) * 64, wc = (wave & 1) * 64;
    const int fr = lane & 15;
    const int fk = (lane >> 4) * 8;
    f32x4 acc[4][4] = {};

    for (int k0 = 0; k0 < K; k0 += 32) {
        __syncthreads();
#pragma unroll
        for (int c = 0; c < 2; ++c) {
            int chunk = wave + c * 4;
            int b = chunk * 1024 + lane * 16;
            int row = b >> 6;
            int ke = (b & 63) >> 1;
            int ra = bm + row; if (ra >= M) ra = M - 1;
            GLOAD_LDS16(A + (size_t)ra * K + k0 + ke, Asm + chunk * 512);
            int rb = bn + row;
            GLOAD_LDS16(W + (size_t)rb * K + k0 + ke, Bsm + chunk * 512);
        }
        __syncthreads();
        s16x8 af[4], bf[4];
#pragma unroll
        for (int i = 0; i < 4; ++i) {
            af[i] = *(const s16x8*)(Asm + (wr + i * 16 + fr) * 32 + fk);
            bf[i] = *(const s16x8*)(Bsm + (wc + i * 16 + fr) * 32 + fk);
        }
#pragma unroll
        for (int mi = 0; mi < 4; ++mi)
#pragma unroll
            for (int ni = 0; ni < 4; ++ni)
                acc[mi][ni] = __builtin_amdgcn_mfma_f32_16x16x32_bf16(
                    af[mi], bf[ni], acc[mi][ni], 0, 0, 0);
    }
    const int cc = lane & 15, cr4 = (lane >> 4) * 4;
#pragma unroll
    for (int mi = 0; mi < 4; ++mi) {
#pragma unroll
        for (int ni = 0; ni < 4; ++ni) {
            int col = bn + wc + ni * 16 + cc;
            float bv = bias[col];
#pragma unroll
            for (int j = 0; j < 4; ++j) {
                int row = bm + wr + mi * 16 + cr4 + j;
                if (row >= M) continue;
                float v = acc[mi][ni][j] + bv;
                if (RELU) v = fmaxf(v, 0.f);
                if (OUTBF16) ((u16*)Cout)[(size_t)row * N + col] = f2b(v);
                else ((float*)Cout)[(size_t)row * N + col] = v;
            }
        }
    }
}

// ---------------------------------------------------------------------------
// fp32 GEMM (small-N off/aw projections): C = A @ W^T + bias
// ---------------------------------------------------------------------------
__global__ __launch_bounds__(256) void gemm_nt(
    const float* __restrict__ A, const float* __restrict__ W,
    const float* __restrict__ bias, float* __restrict__ C,
    int M, int N, int K, int relu)
{
    __shared__ float As[64][33];
    __shared__ float Ws[64][33];
    const int bm = blockIdx.y << 6, bn = blockIdx.x << 6;
    const int tid = threadIdx.x;
    const int tx = tid & 15, ty = tid >> 4;
    float acc[4][4] = {};
    for (int k0 = 0; k0 < K; k0 += 32) {
#pragma unroll
        for (int s = 0; s < 2; ++s) {
            int item = tid + s * 256;
            int row = item >> 3, kv = (item & 7) << 2;
            int gr = bm + row;
            float4 v = make_float4(0.f, 0.f, 0.f, 0.f);
            if (gr < M) v = *(const float4*)(A + (size_t)gr * K + k0 + kv);
            As[row][kv + 0] = v.x; As[row][kv + 1] = v.y;
            As[row][kv + 2] = v.z; As[row][kv + 3] = v.w;
            int gn = bn + row;
            float4 u = make_float4(0.f, 0.f, 0.f, 0.f);
            if (gn < N) u = *(const float4*)(W + (size_t)gn * K + k0 + kv);
            Ws[row][kv + 0] = u.x; Ws[row][kv + 1] = u.y;
            Ws[row][kv + 2] = u.z; Ws[row][kv + 3] = u.w;
        }
        __syncthreads();
#pragma unroll
        for (int kk = 0; kk < 32; ++kk) {
            float a0 = As[ty * 4 + 0][kk], a1 = As[ty * 4 + 1][kk];
            float a2 = As[ty * 4 + 2][kk], a3 = As[ty * 4 + 3][kk];
            float w0 = Ws[tx * 4 + 0][kk], w1 = Ws[tx * 4 + 1][kk];
            float w2 = Ws[tx * 4 + 2][kk], w3 = Ws[tx * 4 + 3][kk];
            acc[0][0] += a0 * w0; acc[0][1] += a0 * w1; acc[0][2] += a0 * w2; acc[0][3] += a0 * w3;
            acc[1][0] += a1 * w0; acc[1][1] += a1 * w1; acc[1][2] += a1 * w2; acc[1][3] += a1 * w3;
            acc[2][0] += a2 * w0; acc[2][1] += a2 * w1; acc[2][2] += a2 * w2; acc[2][3] += a2 * w3;
            acc[3][0] += a3 * w0; acc[3][1] += a3 * w1; acc[3][2] += a3 * w2; acc[3][3] += a3 * w3;
        }
        __syncthreads();
    }
#pragma unroll
    for (int i = 0; i < 4; ++i) {
        int gr = bm + ty * 4 + i;
        if (gr >= M) continue;
#pragma unroll
        for (int j = 0; j < 4; ++j) {
            int gn = bn + tx * 4 + j;
            if (gn >= N) continue;
            float v = acc[i][j] + bias[gn];
            if (relu) v = fmaxf(v, 0.f);
            C[(size_t)gr * N + gn] = v;
        }
    }
}

// ---------------------------------------------------------------------------
// MFMA flash attention. qkv[BI*300][768] bf16 (q|k|v per head h at h*32).
// Block = (bi, h, seg). 4 waves; wave owns q-tiles of 16, online softmax
// over 10 k-chunks of 32. One mfma_16x16x32 per 16x16 S tile (d==32==K).
// ---------------------------------------------------------------------------
__global__ __launch_bounds__(256) void attn_mfma(
    const u16* __restrict__ qkv, u16* __restrict__ O, int S)
{
    const int bh = blockIdx.x / S, seg = blockIdx.x % S;
    const int bi = bh >> 3, h = bh & 7;
    __shared__ u16 Ks[320][40];    // K * scale, row-major
    __shared__ u16 Vt[32][328];    // V transposed [d][k]
    __shared__ u16 Pb[4][16][40];  // per-wave P relayout buffer
    const int tid = threadIdx.x;
    const float scale = 0.17677669529663687f;  // 1/sqrt(32)

    // stage K (pre-scaled) and V(transposed)
    for (int idx = tid; idx < 1200; idx += 256) {
        int k = idx >> 2, sub = idx & 3;
        const u16* kp = qkv + ((size_t)(bi * 300 + k)) * 768 + 256 + h * 32 + sub * 8;
        u16 tmp[8], ks[8];
        *(uint4*)tmp = *(const uint4*)kp;
#pragma unroll
        for (int j = 0; j < 8; ++j) ks[j] = f2b(b2f(tmp[j]) * scale);
        *(uint4*)&Ks[k][sub * 8] = *(const uint4*)ks;
        *(uint4*)tmp = *(const uint4*)(kp + 256);
#pragma unroll
        for (int j = 0; j < 8; ++j) Vt[sub * 8 + j][k] = tmp[j];
    }
    // zero V tail (k = 300..319) so padded PV contributions are exactly 0
    for (int idx = tid; idx < 32 * 20; idx += 256)
        Vt[idx / 20][300 + idx % 20] = 0;
    __syncthreads();

    const int lane = tid & 63, wave = tid >> 6;
    const int c = lane & 15, g = lane >> 4;
    const int fk = g * 8;
    const f32x4 zero = { 0.f, 0.f, 0.f, 0.f };

    for (int qt = seg * 4 + wave; qt < 19; qt += 4 * S) {
        int qrow = qt * 16 + c; if (qrow > 299) qrow = 299;
        s16x8 afq = *(const s16x8*)(qkv + ((size_t)(bi * 300 + qrow)) * 768 + h * 32 + fk);
        f32x4 acc0 = zero, acc1 = zero;
        float m[4] = { -1e30f, -1e30f, -1e30f, -1e30f };
        float l[4] = { 0.f, 0.f, 0.f, 0.f };

        for (int kc = 0; kc < 10; ++kc) {
            const int kb = kc * 32;
            s16x8 bf0 = *(const s16x8*)&Ks[kb + c][fk];
            s16x8 bf1 = *(const s16x8*)&Ks[kb + 16 + c][fk];
            f32x4 s0 = __builtin_amdgcn_mfma_f32_16x16x32_bf16(afq, bf0, zero, 0, 0, 0);
            f32x4 s1 = __builtin_amdgcn_mfma_f32_16x16x32_bf16(afq, bf1, zero, 0, 0, 0);
            if (kb == 288) {
                // mask padded keys (k >= 300); overwrite kills any NaN from garbage LDS
                bool inv0 = (288 + c) >= 300;
#pragma unroll
                for (int j = 0; j < 4; ++j) {
                    if (inv0) s0[j] = -1e30f;
                    s1[j] = -1e30f;
                }
            }
            // chunk row-max (rows live in lanes sharing g; 16-lane xor reduce)
            float cm[4];
#pragma unroll
            for (int j = 0; j < 4; ++j) cm[j] = fmaxf(s0[j], s1[j]);
#pragma unroll
            for (int o = 1; o < 16; o <<= 1)
#pragma unroll
                for (int j = 0; j < 4; ++j) cm[j] = fmaxf(cm[j], __shfl_xor(cm[j], o));
            float corr[4];
#pragma unroll
            for (int j = 0; j < 4; ++j) {
                float mn = fmaxf(m[j], cm[j]);
                corr[j] = __expf(m[j] - mn);
                m[j] = mn;
            }
#pragma unroll
            for (int j = 0; j < 4; ++j) {
                s0[j] = __expf(s0[j] - m[j]);
                s1[j] = __expf(s1[j] - m[j]);
            }
            float cs[4];
#pragma unroll
            for (int j = 0; j < 4; ++j) cs[j] = s0[j] + s1[j];
#pragma unroll
            for (int o = 1; o < 16; o <<= 1)
#pragma unroll
                for (int j = 0; j < 4; ++j) cs[j] += __shfl_xor(cs[j], o);
#pragma unroll
            for (int j = 0; j < 4; ++j) {
                l[j] = l[j] * corr[j] + cs[j];
                acc0[j] *= corr[j];
                acc1[j] *= corr[j];
            }
            // P chunk -> bf16 -> per-wave LDS relayout (rows = q-in-tile)
#pragma unroll
            for (int j = 0; j < 4; ++j) {
                Pb[wave][g * 4 + j][c]      = f2b(s0[j]);
                Pb[wave][g * 4 + j][16 + c] = f2b(s1[j]);
            }
            s16x8 afp = *(const s16x8*)&Pb[wave][c][fk];
            s16x8 bv0 = *(const s16x8*)&Vt[c][kb + fk];
            s16x8 bv1 = *(const s16x8*)&Vt[16 + c][kb + fk];
            acc0 = __builtin_amdgcn_mfma_f32_16x16x32_bf16(afp, bv0, acc0, 0, 0, 0);
            acc1 = __builtin_amdgcn_mfma_f32_16x16x32_bf16(afp, bv1, acc1, 0, 0, 0);
        }
        // epilogue: normalize and store
#pragma unroll
        for (int j = 0; j < 4; ++j) {
            int q = qt * 16 + g * 4 + j;
            if (q < 300) {
                float r = 1.f / l[j];
                u16* op = O + ((size_t)(bi * 300 + q)) * 256 + h * 32;
                op[c]      = f2b(acc0[j] * r);
                op[16 + c] = f2b(acc1[j] * r);
            }
        }
    }
}

// sc_x[(b*16+nc)*300+nq][c] = sub_contour_query[b][nq][nc][c]  (bf16 out)
__global__ __launch_bounds__(256) void sc_transpose(
    const float* __restrict__ scq, u16* __restrict__ out)
{
    int row = blockIdx.x;
    int b = row / 4800;
    int rem = row % 4800;
    int nc = rem / 300, nq = rem % 300;
    int c = threadIdx.x;
    out[(size_t)row * 256 + c] = f2b(scq[((size_t)((b * 300 + nq) * 16 + nc)) * 256 + c]);
}

// tgt = LN( scq + 2*(sc_o + inst_o) ) with n1
__global__ __launch_bounds__(256) void ln1_combine(
    const float* __restrict__ scq, const float* __restrict__ sco,
    const float* __restrict__ insto, const float* __restrict__ g,
    const float* __restrict__ bta, float* __restrict__ tgt)
{
    __shared__ float sb[8];
    int row = blockIdx.x;
    int b = row / 4800;
    int rem = row % 4800;
    int nq = rem >> 4, nc = rem & 15;
    int c = threadIdx.x;
    float v = scq[(size_t)row * 256 + c]
            + 2.f * (sco[((size_t)((b * 16 + nc) * 300 + nq)) * 256 + c]
                   + insto[((size_t)(b * 300 + nq)) * 256 + c]);
    float mean, rstd;
    block_meanvar(v, sb, mean, rstd);
    tgt[(size_t)row * 256 + c] = (v - mean) * rstd * g[c] + bta[c];
}

// dst = LN(x + y); optional bf16 copy
__global__ __launch_bounds__(256) void ln_add(
    const float* __restrict__ x, const float* __restrict__ y,
    const float* __restrict__ g, const float* __restrict__ bta,
    float* __restrict__ dst, u16* __restrict__ bdst)
{
    __shared__ float sb[8];
    int row = blockIdx.x;
    int c = threadIdx.x;
    float v = x[(size_t)row * 256 + c] + y[(size_t)row * 256 + c];
    float mean, rstd;
    block_meanvar(v, sb, mean, rstd);
    float r = (v - mean) * rstd * g[c] + bta[c];
    dst[(size_t)row * 256 + c] = r;
    if (bdst) bdst[(size_t)row * 256 + c] = f2b(r);
}

// deformable bilinear sampling + aw-softmax reduce over NP=4 (bf16 out)
__global__ __launch_bounds__(256) void deform_sample(
    const float* __restrict__ offb, const float* __restrict__ awb,
    const float* __restrict__ refb, const float* __restrict__ mem,
    const int* __restrict__ Hp, const int* __restrict__ Wp,
    u16* __restrict__ samp)
{
    const int row = blockIdx.x;
    const int b = row / 4800;
    const int tid = threadIdx.x;
    const int h = tid >> 5;
    const int H = *Hp, Wd = *Wp;
    const float4 rb = *(const float4*)(refb + (size_t)row * 4);
    const float* awp = awb + (size_t)row * 32 + h * 4;
    float a0 = awp[0], a1 = awp[1], a2 = awp[2], a3 = awp[3];
    float am = fmaxf(fmaxf(a0, a1), fmaxf(a2, a3));
    float e0 = __expf(a0 - am), e1 = __expf(a1 - am), e2 = __expf(a2 - am), e3 = __expf(a3 - am);
    float rs = 1.f / (e0 + e1 + e2 + e3);
    float wp[4] = { e0 * rs, e1 * rs, e2 * rs, e3 * rs };
    const float* op = offb + (size_t)row * 64 + h * 8;
    const float* mb = mem + (size_t)b * H * Wd * 256 + tid;
    float acc = 0.f;
#pragma unroll
    for (int p = 0; p < 4; ++p) {
        float ox = op[p * 2 + 0], oy = op[p * 2 + 1];
        float lx = rb.x + ox * rb.z * 0.5f;
        float ly = rb.y + oy * rb.w * 0.5f;
        float gx = lx * (float)Wd - 0.5f;
        float gy = ly * (float)H - 0.5f;
        float x0f = floorf(gx), y0f = floorf(gy);
        int x0 = (int)x0f, y0 = (int)y0f;
        float wx1 = gx - x0f, wy1 = gy - y0f;
        float wx0 = 1.f - wx1, wy0 = 1.f - wy1;
        float v = 0.f;
#pragma unroll
        for (int cy = 0; cy < 2; ++cy) {
            int yi = y0 + cy;
            if ((unsigned)yi >= (unsigned)H) continue;
            float wy = cy ? wy1 : wy0;
#pragma unroll
            for (int cx = 0; cx < 2; ++cx) {
                int xi = x0 + cx;
                if ((unsigned)xi >= (unsigned)Wd) continue;
                float wx = cx ? wx1 : wx0;
                v += wx * wy * mb[(size_t)(yi * Wd + xi) * 256];
            }
        }
        acc += wp[p] * v;
    }
    samp[(size_t)row * 256 + tid] = f2b(acc);
}

extern "C" void kernel_launch(void* const* d_in, const int* in_sizes, int n_in,
                              void* d_out, int out_size, void* d_ws, size_t ws_size,
                              hipStream_t stream) {
    const float* inst_query = (const float*)d_in[0];
    const float* sub_contour = (const float*)d_in[1];
    const float* memory_feats = (const float*)d_in[2];
    const float* ref_boxes = (const float*)d_in[3];
    const float* inst_in_w = (const float*)d_in[4];
    const float* inst_in_b = (const float*)d_in[5];
    const float* inst_out_w = (const float*)d_in[6];
    const float* inst_out_b = (const float*)d_in[7];
    const float* sc_in_w = (const float*)d_in[8];
    const float* sc_in_b = (const float*)d_in[9];
    const float* sc_out_w = (const float*)d_in[10];
    const float* sc_out_b = (const float*)d_in[11];
    const float* off_w = (const float*)d_in[12];
    const float* off_b = (const float*)d_in[13];
    const float* aw_w = (const float*)d_in[14];
    const float* aw_b = (const float*)d_in[15];
    const float* outp_w = (const float*)d_in[16];
    const float* outp_b = (const float*)d_in[17];
    const float* lin1_w = (const float*)d_in[18];
    const float* lin1_b = (const float*)d_in[19];
    const float* lin2_w = (const float*)d_in[20];
    const float* lin2_b = (const float*)d_in[21];
    const float* n1_g = (const float*)d_in[22];
    const float* n1_b = (const float*)d_in[23];
    const float* n2_g = (const float*)d_in[24];
    const float* n2_b = (const float*)d_in[25];
    const float* n3_g = (const float*)d_in[26];
    const float* n3_b = (const float*)d_in[27];
    const int* Hp = (const int*)d_in[28];
    const int* Wp = (const int*)d_in[29];

    // ---- workspace layout ----
    u16* wsb = (u16*)d_ws;
    u16* qkv_b   = wsb;                       // 19200*768  = 14,745,600
    u16* xbuf_b  = qkv_b + 14745600;          // 19200*256  =  4,915,200
    u16* obuf_b  = xbuf_b + 4915200;          //  4,915,200
    u16* tgt_b   = obuf_b + 4915200;          //  4,915,200
    u16* w_inst_in  = tgt_b + 4915200;        //    196,608
    u16* w_inst_out = w_inst_in + 196608;     //     65,536
    u16* w_sc_in    = w_inst_out + 65536;     //    196,608
    u16* w_sc_out   = w_sc_in + 196608;       //     65,536
    u16* w_outp     = w_sc_out + 65536;       //     65,536
    u16* w_lin1     = w_outp + 65536;         //    524,288
    u16* w_lin2     = w_lin1 + 524288;        //    524,288
    u16* ffn1_b = qkv_b;                      // alias
    u16* instq_b = tgt_b;                     // temp (tgt_b not live yet)
    float* fp    = (float*)(w_lin2 + 524288);
    float* insto = fp;                        //    307,200
    float* tgt   = insto + 307200;            //  4,915,200
    float* t2    = tgt + 4915200;             //  4,915,200
    float* offb  = t2 + 4915200;              //  1,228,800
    float* awb   = offb + 1228800;            //    614,400

    dim3 blk(256);

    // fused weight/activation conversions (one launch)
    Cvt8 ca;
    ca.s[0] = { inst_in_w,  w_inst_in,  196608 / 8 };
    ca.s[1] = { inst_out_w, w_inst_out, 65536 / 8 };
    ca.s[2] = { sc_in_w,    w_sc_in,    196608 / 8 };
    ca.s[3] = { sc_out_w,   w_sc_out,   65536 / 8 };
    ca.s[4] = { outp_w,     w_outp,     65536 / 8 };
    ca.s[5] = { lin1_w,     w_lin1,     524288 / 8 };
    ca.s[6] = { lin2_w,     w_lin2,     524288 / 8 };
    ca.s[7] = { inst_query, instq_b,    307200 / 8 };
    int totalv = (196608 * 2 + 65536 * 3 + 524288 * 2 + 307200) / 8;
    cvt_multi<<<(totalv + 255) / 256, blk, 0, stream>>>(ca, totalv);

    // 1. inst QKV (1200x768x256) -> qkv_b (bf16)
    gemm_mfma<0,1><<<dim3(6, 10), blk, 0, stream>>>(instq_b, w_inst_in, inst_in_b, qkv_b, 1200, 768, 256);
    // 2. inst attention (4 bi x 8 h x S=4)
    attn_mfma<<<128, blk, 0, stream>>>(qkv_b, obuf_b, 4);
    // 3. inst out-proj -> insto (fp32)
    gemm_mfma<0,0><<<dim3(2, 10), blk, 0, stream>>>(obuf_b, w_inst_out, inst_out_b, insto, 1200, 256, 256);
    // 4. sc transpose -> xbuf_b (bf16)
    sc_transpose<<<19200, blk, 0, stream>>>(sub_contour, xbuf_b);
    // 5. sc QKV (19200x768x256) -> qkv_b
    gemm_mfma<0,1><<<dim3(6, 150), blk, 0, stream>>>(xbuf_b, w_sc_in, sc_in_b, qkv_b, 19200, 768, 256);
    // 6. sc attention (64 bi x 8 h x S=2)
    attn_mfma<<<1024, blk, 0, stream>>>(qkv_b, obuf_b, 2);
    // 7. sc out-proj -> t2 (fp32, sc row order)
    gemm_mfma<0,0><<<dim3(2, 150), blk, 0, stream>>>(obuf_b, w_sc_out, sc_out_b, t2, 19200, 256, 256);
    // 8. combine + LN1 -> tgt (fp32)
    ln1_combine<<<19200, blk, 0, stream>>>(sub_contour, t2, insto, n1_g, n1_b, tgt);
    // 9. offsets / attention-weights projections (fp32, small N)
    gemm_nt<<<dim3(1, 300), blk, 0, stream>>>(tgt, off_w, off_b, offb, 19200, 64, 256, 0);
    gemm_nt<<<dim3(1, 300), blk, 0, stream>>>(tgt, aw_w, aw_b, awb, 19200, 32, 256, 0);
    // 10. deformable sampling -> obuf_b (bf16)
    deform_sample<<<19200, blk, 0, stream>>>(offb, awb, ref_boxes, memory_feats, Hp, Wp, obuf_b);
    // 11. outp proj -> t2
    gemm_mfma<0,0><<<dim3(2, 150), blk, 0, stream>>>(obuf_b, w_outp, outp_b, t2, 19200, 256, 256);
    // 12. LN2 -> tgt (fp32) + tgt_b (bf16)
    ln_add<<<19200, blk, 0, stream>>>(tgt, t2, n2_g, n2_b, tgt, tgt_b);
    // 13. FFN in 2 chunks of 9600 rows (ffn1_b aliases dead qkv_b+xbuf_b)
    for (int c = 0; c < 2; ++c) {
        gemm_mfma<1,1><<<dim3(16, 75), blk, 0, stream>>>(tgt_b + (size_t)c * 9600 * 256, w_lin1, lin1_b, ffn1_b, 9600, 2048, 256);
        gemm_mfma<0,0><<<dim3(2, 75), blk, 0, stream>>>(ffn1_b, w_lin2, lin2_b, t2 + (size_t)c * 9600 * 256, 9600, 256, 2048);
    }
    // 14. LN3 -> output fp32 (B, NQ, NC, C)
    ln_add<<<19200, blk, 0, stream>>>(tgt, t2, n3_g, n3_b, (float*)d_out, nullptr);
}

// Round 4
// 439.688 us; speedup vs baseline: 5.3004x; 1.1882x over previous
//
#include <hip/hip_runtime.h>
#include <hip/hip_bf16.h>
#include <math.h>

// B=4, NQ=300, NC=16, C=256, NH=8, NP=4, DFF=2048, H=W=128, Lq=4800, hd=32

typedef unsigned short u16;
typedef unsigned int u32;
typedef __attribute__((ext_vector_type(4))) float f32x4;
typedef __attribute__((ext_vector_type(8))) short s16x8;

__device__ __forceinline__ float b2f(u16 u) {
    union { u32 u; float f; } v; v.u = ((u32)u) << 16; return v.f;
}
__device__ __forceinline__ u16 f2b(float f) {
    union { float f; u32 u; } v; v.f = f;
    u32 r = v.u + 0x7fffu + ((v.u >> 16) & 1u);
    return (u16)(r >> 16);
}

// mean/var over 256 elements, block = 256 threads (4 waves)
__device__ __forceinline__ void block_meanvar(float v, float* sb, float& mean, float& rstd) {
    float s = v, s2 = v * v;
#pragma unroll
    for (int o = 32; o; o >>= 1) { s += __shfl_xor(s, o); s2 += __shfl_xor(s2, o); }
    int wv = threadIdx.x >> 6;
    if ((threadIdx.x & 63) == 0) { sb[wv] = s; sb[4 + wv] = s2; }
    __syncthreads();
    s  = sb[0] + sb[1] + sb[2] + sb[3];
    s2 = sb[4] + sb[5] + sb[6] + sb[7];
    mean = s * (1.f / 256.f);
    float var = s2 * (1.f / 256.f) - mean * mean;
    rstd = 1.f / sqrtf(var + 1e-5f);
    __syncthreads();
}

#define GLOAD_LDS16(g, l) \
    __builtin_amdgcn_global_load_lds((const __attribute__((address_space(1))) void*)(g), \
                                     (__attribute__((address_space(3))) void*)(l), 16, 0, 0)

// ---------------------------------------------------------------------------
// Fused fp32 -> bf16 conversion over up to 8 segments (all sizes % 8 == 0)
// ---------------------------------------------------------------------------
struct CvtSeg { const float* src; u16* dst; int nv; };  // nv = elems/8
struct Cvt8 { CvtSeg s[8]; };

__global__ __launch_bounds__(256) void cvt_multi(Cvt8 a, int totalv) {
    int v = blockIdx.x * 256 + threadIdx.x;
    if (v >= totalv) return;
    int si = 0;
    while (si < 7 && v >= a.s[si].nv) { v -= a.s[si].nv; ++si; }
    const float* src = a.s[si].src + (size_t)v * 8;
    u16* dst = a.s[si].dst + (size_t)v * 8;
    float4 x = *(const float4*)src;
    float4 y = *(const float4*)(src + 4);
    u16 u[8] = { f2b(x.x), f2b(x.y), f2b(x.z), f2b(x.w),
                 f2b(y.x), f2b(y.y), f2b(y.z), f2b(y.w) };
    *(uint4*)dst = *(const uint4*)u;
}

// pack off_w(64) + aw_w(32) + zeros(32) -> [128][256] bf16, bias -> [128] f32
__global__ __launch_bounds__(256) void pack_offaw(
    const float* __restrict__ off_w, const float* __restrict__ off_b,
    const float* __restrict__ aw_w, const float* __restrict__ aw_b,
    u16* __restrict__ wout, float* __restrict__ bout)
{
    int r = blockIdx.x, c = threadIdx.x;
    float v = 0.f;
    if (r < 64) v = off_w[r * 256 + c];
    else if (r < 96) v = aw_w[(r - 64) * 256 + c];
    wout[r * 256 + c] = f2b(v);
    if (c == 0) bout[r] = (r < 64) ? off_b[r] : (r < 96 ? aw_b[r - 64] : 0.f);
}

// ---------------------------------------------------------------------------
// MFMA bf16 GEMM: C[M,N] = A[M,K] @ W[N,K]^T + bias (128x128, BK=32)
// ---------------------------------------------------------------------------
template<int RELU, int OUTBF16>
__global__ __launch_bounds__(256) void gemm_mfma(
    const u16* __restrict__ A, const u16* __restrict__ W,
    const float* __restrict__ bias, void* __restrict__ Cout,
    int M, int N, int K)
{
    __shared__ u16 Asm[128 * 32];
    __shared__ u16 Bsm[128 * 32];
    const int tid = threadIdx.x;
    const int wave = tid >> 6, lane = tid & 63;
    const int bm = blockIdx.y * 128, bn = blockIdx.x * 128;
    const int wr = (wave >> 1) * 64, wc = (wave & 1) * 64;
    const int fr = lane & 15;
    const int fk = (lane >> 4) * 8;
    f32x4 acc[4][4] = {};

    for (int k0 = 0; k0 < K; k0 += 32) {
        __syncthreads();
#pragma unroll
        for (int c = 0; c < 2; ++c) {
            int chunk = wave + c * 4;
            int b = chunk * 1024 + lane * 16;
            int row = b >> 6;
            int ke = (b & 63) >> 1;
            int ra = bm + row; if (ra >= M) ra = M - 1;
            GLOAD_LDS16(A + (size_t)ra * K + k0 + ke, Asm + chunk * 512);
            int rb = bn + row;
            GLOAD_LDS16(W + (size_t)rb * K + k0 + ke, Bsm + chunk * 512);
        }
        __syncthreads();
        s16x8 af[4], bf[4];
#pragma unroll
        for (int i = 0; i < 4; ++i) {
            af[i] = *(const s16x8*)(Asm + (wr + i * 16 + fr) * 32 + fk);
            bf[i] = *(const s16x8*)(Bsm + (wc + i * 16 + fr) * 32 + fk);
        }
#pragma unroll
        for (int mi = 0; mi < 4; ++mi)
#pragma unroll
            for (int ni = 0; ni < 4; ++ni)
                acc[mi][ni] = __builtin_amdgcn_mfma_f32_16x16x32_bf16(
                    af[mi], bf[ni], acc[mi][ni], 0, 0, 0);
    }
    const int cc = lane & 15, cr4 = (lane >> 4) * 4;
#pragma unroll
    for (int mi = 0; mi < 4; ++mi) {
#pragma unroll
        for (int ni = 0; ni < 4; ++ni) {
            int col = bn + wc + ni * 16 + cc;
            float bv = bias[col];
#pragma unroll
            for (int j = 0; j < 4; ++j) {
                int row = bm + wr + mi * 16 + cr4 + j;
                if (row >= M) continue;
                float v = acc[mi][ni][j] + bv;
                if (RELU) v = fmaxf(v, 0.f);
                if (OUTBF16) ((u16*)Cout)[(size_t)row * N + col] = f2b(v);
                else ((float*)Cout)[(size_t)row * N + col] = v;
            }
        }
    }
}

// ---------------------------------------------------------------------------
// MFMA flash attention. qkv[BI*300][768] bf16 (q|k|v per head h at h*32).
// ---------------------------------------------------------------------------
__global__ __launch_bounds__(256) void attn_mfma(
    const u16* __restrict__ qkv, u16* __restrict__ O, int S)
{
    const int bh = blockIdx.x / S, seg = blockIdx.x % S;
    const int bi = bh >> 3, h = bh & 7;
    __shared__ u16 Ks[320][40];    // K * scale, row-major
    __shared__ u16 Vt[32][328];    // V transposed [d][k]
    __shared__ u16 Pb[4][16][40];  // per-wave P relayout buffer
    const int tid = threadIdx.x;
    const float scale = 0.17677669529663687f;  // 1/sqrt(32)

    for (int idx = tid; idx < 1200; idx += 256) {
        int k = idx >> 2, sub = idx & 3;
        const u16* kp = qkv + ((size_t)(bi * 300 + k)) * 768 + 256 + h * 32 + sub * 8;
        u16 tmp[8], ks[8];
        *(uint4*)tmp = *(const uint4*)kp;
#pragma unroll
        for (int j = 0; j < 8; ++j) ks[j] = f2b(b2f(tmp[j]) * scale);
        *(uint4*)&Ks[k][sub * 8] = *(const uint4*)ks;
        *(uint4*)tmp = *(const uint4*)(kp + 256);
#pragma unroll
        for (int j = 0; j < 8; ++j) Vt[sub * 8 + j][k] = tmp[j];
    }
    for (int idx = tid; idx < 32 * 20; idx += 256)
        Vt[idx / 20][300 + idx % 20] = 0;
    __syncthreads();

    const int lane = tid & 63, wave = tid >> 6;
    const int c = lane & 15, g = lane >> 4;
    const int fk = g * 8;
    const f32x4 zero = { 0.f, 0.f, 0.f, 0.f };

    for (int qt = seg * 4 + wave; qt < 19; qt += 4 * S) {
        int qrow = qt * 16 + c; if (qrow > 299) qrow = 299;
        s16x8 afq = *(const s16x8*)(qkv + ((size_t)(bi * 300 + qrow)) * 768 + h * 32 + fk);
        f32x4 acc0 = zero, acc1 = zero;
        float m[4] = { -1e30f, -1e30f, -1e30f, -1e30f };
        float l[4] = { 0.f, 0.f, 0.f, 0.f };

        for (int kc = 0; kc < 10; ++kc) {
            const int kb = kc * 32;
            s16x8 bf0 = *(const s16x8*)&Ks[kb + c][fk];
            s16x8 bf1 = *(const s16x8*)&Ks[kb + 16 + c][fk];
            f32x4 s0 = __builtin_amdgcn_mfma_f32_16x16x32_bf16(afq, bf0, zero, 0, 0, 0);
            f32x4 s1 = __builtin_amdgcn_mfma_f32_16x16x32_bf16(afq, bf1, zero, 0, 0, 0);
            if (kb == 288) {
                bool inv0 = (288 + c) >= 300;
#pragma unroll
                for (int j = 0; j < 4; ++j) {
                    if (inv0) s0[j] = -1e30f;
                    s1[j] = -1e30f;
                }
            }
            float cm[4];
#pragma unroll
            for (int j = 0; j < 4; ++j) cm[j] = fmaxf(s0[j], s1[j]);
#pragma unroll
            for (int o = 1; o < 16; o <<= 1)
#pragma unroll
                for (int j = 0; j < 4; ++j) cm[j] = fmaxf(cm[j], __shfl_xor(cm[j], o));
            float corr[4];
#pragma unroll
            for (int j = 0; j < 4; ++j) {
                float mn = fmaxf(m[j], cm[j]);
                corr[j] = __expf(m[j] - mn);
                m[j] = mn;
            }
#pragma unroll
            for (int j = 0; j < 4; ++j) {
                s0[j] = __expf(s0[j] - m[j]);
                s1[j] = __expf(s1[j] - m[j]);
            }
            float cs[4];
#pragma unroll
            for (int j = 0; j < 4; ++j) cs[j] = s0[j] + s1[j];
#pragma unroll
            for (int o = 1; o < 16; o <<= 1)
#pragma unroll
                for (int j = 0; j < 4; ++j) cs[j] += __shfl_xor(cs[j], o);
#pragma unroll
            for (int j = 0; j < 4; ++j) {
                l[j] = l[j] * corr[j] + cs[j];
                acc0[j] *= corr[j];
                acc1[j] *= corr[j];
            }
#pragma unroll
            for (int j = 0; j < 4; ++j) {
                Pb[wave][g * 4 + j][c]      = f2b(s0[j]);
                Pb[wave][g * 4 + j][16 + c] = f2b(s1[j]);
            }
            s16x8 afp = *(const s16x8*)&Pb[wave][c][fk];
            s16x8 bv0 = *(const s16x8*)&Vt[c][kb + fk];
            s16x8 bv1 = *(const s16x8*)&Vt[16 + c][kb + fk];
            acc0 = __builtin_amdgcn_mfma_f32_16x16x32_bf16(afp, bv0, acc0, 0, 0, 0);
            acc1 = __builtin_amdgcn_mfma_f32_16x16x32_bf16(afp, bv1, acc1, 0, 0, 0);
        }
#pragma unroll
        for (int j = 0; j < 4; ++j) {
            int q = qt * 16 + g * 4 + j;
            if (q < 300) {
                float r = 1.f / l[j];
                u16* op = O + ((size_t)(bi * 300 + q)) * 256 + h * 32;
                op[c]      = f2b(acc0[j] * r);
                op[16 + c] = f2b(acc1[j] * r);
            }
        }
    }
}

// sc_x[(b*16+nc)*300+nq][c] = sub_contour_query[b][nq][nc][c]  (bf16 out)
__global__ __launch_bounds__(256) void sc_transpose(
    const float* __restrict__ scq, u16* __restrict__ out)
{
    int row = blockIdx.x;
    int b = row / 4800;
    int rem = row % 4800;
    int nc = rem / 300, nq = rem % 300;
    int c = threadIdx.x;
    out[(size_t)row * 256 + c] = f2b(scq[((size_t)((b * 300 + nq) * 16 + nc)) * 256 + c]);
}

// tgt = LN( scq + 2*(sc_o + inst_o) ) with n1; emits fp32 + bf16
__global__ __launch_bounds__(256) void ln1_combine(
    const float* __restrict__ scq, const float* __restrict__ sco,
    const float* __restrict__ insto, const float* __restrict__ g,
    const float* __restrict__ bta, float* __restrict__ tgt,
    u16* __restrict__ tgtb)
{
    __shared__ float sb[8];
    int row = blockIdx.x;
    int b = row / 4800;
    int rem = row % 4800;
    int nq = rem >> 4, nc = rem & 15;
    int c = threadIdx.x;
    float v = scq[(size_t)row * 256 + c]
            + 2.f * (sco[((size_t)((b * 16 + nc) * 300 + nq)) * 256 + c]
                   + insto[((size_t)(b * 300 + nq)) * 256 + c]);
    float mean, rstd;
    block_meanvar(v, sb, mean, rstd);
    float r = (v - mean) * rstd * g[c] + bta[c];
    tgt[(size_t)row * 256 + c] = r;
    tgtb[(size_t)row * 256 + c] = f2b(r);
}

// dst = LN(x + y); optional bf16 copy
__global__ __launch_bounds__(256) void ln_add(
    const float* __restrict__ x, const float* __restrict__ y,
    const float* __restrict__ g, const float* __restrict__ bta,
    float* __restrict__ dst, u16* __restrict__ bdst)
{
    __shared__ float sb[8];
    int row = blockIdx.x;
    int c = threadIdx.x;
    float v = x[(size_t)row * 256 + c] + y[(size_t)row * 256 + c];
    float mean, rstd;
    block_meanvar(v, sb, mean, rstd);
    float r = (v - mean) * rstd * g[c] + bta[c];
    dst[(size_t)row * 256 + c] = r;
    if (bdst) bdst[(size_t)row * 256 + c] = f2b(r);
}

// ---------------------------------------------------------------------------
// deformable bilinear sampling + aw-softmax reduce over NP=4 (bf16 out).
// H=W=128 hardcoded (fixed problem constants). Branchless: clamped addresses,
// zeroed weights for OOB corners; all 16 loads batched for ILP.
// oaw[row][128]: cols 0..63 = offsets (h*8 + p*2 + {x,y}), 64..95 = aw.
// ---------------------------------------------------------------------------
__global__ __launch_bounds__(256) void deform_sample(
    const float* __restrict__ oaw, const float* __restrict__ refb,
    const float* __restrict__ mem, u16* __restrict__ samp)
{
    const int row = blockIdx.x;
    const int b = row / 4800;
    const int tid = threadIdx.x;
    const int h = tid >> 5;
    const float4 rb = *(const float4*)(refb + (size_t)row * 4);
    const float* base = oaw + (size_t)row * 128;
    float a0 = base[64 + h * 4 + 0], a1 = base[64 + h * 4 + 1];
    float a2 = base[64 + h * 4 + 2], a3 = base[64 + h * 4 + 3];
    float am = fmaxf(fmaxf(a0, a1), fmaxf(a2, a3));
    float e0 = __expf(a0 - am), e1 = __expf(a1 - am), e2 = __expf(a2 - am), e3 = __expf(a3 - am);
    float rs = 1.f / (e0 + e1 + e2 + e3);
    float wp[4] = { e0 * rs, e1 * rs, e2 * rs, e3 * rs };
    const float* op = base + h * 8;
    const float* mb = mem + (size_t)b * 16384 * 256 + tid;

    int offs[16];
    float wts[16];
#pragma unroll
    for (int p = 0; p < 4; ++p) {
        float gx = (rb.x + op[p * 2 + 0] * rb.z * 0.5f) * 128.f - 0.5f;
        float gy = (rb.y + op[p * 2 + 1] * rb.w * 0.5f) * 128.f - 0.5f;
        float x0f = floorf(gx), y0f = floorf(gy);
        int x0 = (int)x0f, y0 = (int)y0f;
        float wx1 = gx - x0f, wy1 = gy - y0f;
        float wx0 = 1.f - wx1, wy0 = 1.f - wy1;
        float vx0 = ((unsigned)x0 < 128u) ? 1.f : 0.f;
        float vx1 = ((unsigned)(x0 + 1) < 128u) ? 1.f : 0.f;
        float vy0 = ((unsigned)y0 < 128u) ? 1.f : 0.f;
        float vy1 = ((unsigned)(y0 + 1) < 128u) ? 1.f : 0.f;
        int xc0 = min(max(x0, 0), 127), xc1 = min(max(x0 + 1, 0), 127);
        int yc0 = min(max(y0, 0), 127), yc1 = min(max(y0 + 1, 0), 127);
        offs[p * 4 + 0] = (yc0 * 128 + xc0) << 8;
        offs[p * 4 + 1] = (yc0 * 128 + xc1) << 8;
        offs[p * 4 + 2] = (yc1 * 128 + xc0) << 8;
        offs[p * 4 + 3] = (yc1 * 128 + xc1) << 8;
        wts[p * 4 + 0] = wp[p] * wx0 * wy0 * vx0 * vy0;
        wts[p * 4 + 1] = wp[p] * wx1 * wy0 * vx1 * vy0;
        wts[p * 4 + 2] = wp[p] * wx0 * wy1 * vx0 * vy1;
        wts[p * 4 + 3] = wp[p] * wx1 * wy1 * vx1 * vy1;
    }
    float vals[16];
#pragma unroll
    for (int i = 0; i < 16; ++i) vals[i] = mb[offs[i]];
    float acc = 0.f;
#pragma unroll
    for (int i = 0; i < 16; ++i) acc = fmaf(vals[i], wts[i], acc);
    samp[(size_t)row * 256 + tid] = f2b(acc);
}

extern "C" void kernel_launch(void* const* d_in, const int* in_sizes, int n_in,
                              void* d_out, int out_size, void* d_ws, size_t ws_size,
                              hipStream_t stream) {
    const float* inst_query = (const float*)d_in[0];
    const float* sub_contour = (const float*)d_in[1];
    const float* memory_feats = (const float*)d_in[2];
    const float* ref_boxes = (const float*)d_in[3];
    const float* inst_in_w = (const float*)d_in[4];
    const float* inst_in_b = (const float*)d_in[5];
    const float* inst_out_w = (const float*)d_in[6];
    const float* inst_out_b = (const float*)d_in[7];
    const float* sc_in_w = (const float*)d_in[8];
    const float* sc_in_b = (const float*)d_in[9];
    const float* sc_out_w = (const float*)d_in[10];
    const float* sc_out_b = (const float*)d_in[11];
    const float* off_w = (const float*)d_in[12];
    const float* off_b = (const float*)d_in[13];
    const float* aw_w = (const float*)d_in[14];
    const float* aw_b = (const float*)d_in[15];
    const float* outp_w = (const float*)d_in[16];
    const float* outp_b = (const float*)d_in[17];
    const float* lin1_w = (const float*)d_in[18];
    const float* lin1_b = (const float*)d_in[19];
    const float* lin2_w = (const float*)d_in[20];
    const float* lin2_b = (const float*)d_in[21];
    const float* n1_g = (const float*)d_in[22];
    const float* n1_b = (const float*)d_in[23];
    const float* n2_g = (const float*)d_in[24];
    const float* n2_b = (const float*)d_in[25];
    const float* n3_g = (const float*)d_in[26];
    const float* n3_b = (const float*)d_in[27];

    // ---- workspace layout ----
    u16* wsb = (u16*)d_ws;
    u16* qkv_b   = wsb;                       // 19200*768  = 14,745,600
    u16* xbuf_b  = qkv_b + 14745600;          //  4,915,200
    u16* obuf_b  = xbuf_b + 4915200;          //  4,915,200
    u16* tgt_b   = obuf_b + 4915200;          //  4,915,200
    u16* w_inst_in  = tgt_b + 4915200;        //    196,608
    u16* w_inst_out = w_inst_in + 196608;     //     65,536
    u16* w_sc_in    = w_inst_out + 65536;     //    196,608
    u16* w_sc_out   = w_sc_in + 196608;       //     65,536
    u16* w_outp     = w_sc_out + 65536;       //     65,536
    u16* w_lin1     = w_outp + 65536;         //    524,288
    u16* w_lin2     = w_lin1 + 524288;        //    524,288
    u16* w_offaw    = w_lin2 + 524288;        //     32,768
    u16* ffn1_b = qkv_b;                      // alias
    u16* instq_b = tgt_b;                     // temp (tgt_b not live yet)
    float* fp    = (float*)(w_offaw + 32768);
    float* insto = fp;                        //    307,200
    float* tgt   = insto + 307200;            //  4,915,200
    float* t2    = tgt + 4915200;             //  4,915,200
    float* oawb  = t2 + 4915200;              //  2,457,600
    float* b_offaw = oawb + 2457600;          //        128

    dim3 blk(256);

    // fused weight/activation conversions
    Cvt8 ca;
    ca.s[0] = { inst_in_w,  w_inst_in,  196608 / 8 };
    ca.s[1] = { inst_out_w, w_inst_out, 65536 / 8 };
    ca.s[2] = { sc_in_w,    w_sc_in,    196608 / 8 };
    ca.s[3] = { sc_out_w,   w_sc_out,   65536 / 8 };
    ca.s[4] = { outp_w,     w_outp,     65536 / 8 };
    ca.s[5] = { lin1_w,     w_lin1,     524288 / 8 };
    ca.s[6] = { lin2_w,     w_lin2,     524288 / 8 };
    ca.s[7] = { inst_query, instq_b,    307200 / 8 };
    int totalv = (196608 * 2 + 65536 * 3 + 524288 * 2 + 307200) / 8;
    cvt_multi<<<(totalv + 255) / 256, blk, 0, stream>>>(ca, totalv);
    pack_offaw<<<128, blk, 0, stream>>>(off_w, off_b, aw_w, aw_b, w_offaw, b_offaw);

    // 1. inst QKV -> qkv_b (bf16)
    gemm_mfma<0,1><<<dim3(6, 10), blk, 0, stream>>>(instq_b, w_inst_in, inst_in_b, qkv_b, 1200, 768, 256);
    // 2. inst attention
    attn_mfma<<<128, blk, 0, stream>>>(qkv_b, obuf_b, 4);
    // 3. inst out-proj -> insto (fp32)
    gemm_mfma<0,0><<<dim3(2, 10), blk, 0, stream>>>(obuf_b, w_inst_out, inst_out_b, insto, 1200, 256, 256);
    // 4. sc transpose -> xbuf_b (bf16)
    sc_transpose<<<19200, blk, 0, stream>>>(sub_contour, xbuf_b);
    // 5. sc QKV
    gemm_mfma<0,1><<<dim3(6, 150), blk, 0, stream>>>(xbuf_b, w_sc_in, sc_in_b, qkv_b, 19200, 768, 256);
    // 6. sc attention
    attn_mfma<<<1024, blk, 0, stream>>>(qkv_b, obuf_b, 2);
    // 7. sc out-proj -> t2 (fp32, sc row order)
    gemm_mfma<0,0><<<dim3(2, 150), blk, 0, stream>>>(obuf_b, w_sc_out, sc_out_b, t2, 19200, 256, 256);
    // 8. combine + LN1 -> tgt (fp32) + tgt_b (bf16)
    ln1_combine<<<19200, blk, 0, stream>>>(sub_contour, t2, insto, n1_g, n1_b, tgt, tgt_b);
    // 9. packed off+aw projection (MFMA) -> oawb [19200][128]
    gemm_mfma<0,0><<<dim3(1, 150), blk, 0, stream>>>(tgt_b, w_offaw, b_offaw, oawb, 19200, 128, 256);
    // 10. deformable sampling -> obuf_b (bf16)
    deform_sample<<<19200, blk, 0, stream>>>(oawb, ref_boxes, memory_feats, obuf_b);
    // 11. outp proj -> t2
    gemm_mfma<0,0><<<dim3(2, 150), blk, 0, stream>>>(obuf_b, w_outp, outp_b, t2, 19200, 256, 256);
    // 12. LN2 -> tgt (fp32) + tgt_b (bf16)
    ln_add<<<19200, blk, 0, stream>>>(tgt, t2, n2_g, n2_b, tgt, tgt_b);
    // 13. FFN in 2 chunks of 9600 rows (ffn1_b aliases dead qkv_b+xbuf_b)
    for (int c = 0; c < 2; ++c) {
        gemm_mfma<1,1><<<dim3(16, 75), blk, 0, stream>>>(tgt_b + (size_t)c * 9600 * 256, w_lin1, lin1_b, ffn1_b, 9600, 2048, 256);
        gemm_mfma<0,0><<<dim3(2, 75), blk, 0, stream>>>(ffn1_b, w_lin2, lin2_b, t2 + (size_t)c * 9600 * 256, 9600, 256, 2048);
    }
    // 14. LN3 -> output fp32 (B, NQ, NC, C)
    ln_add<<<19200, blk, 0, stream>>>(tgt, t2, n3_g, n3_b, (float*)d_out, nullptr);
}

// Round 5
// 416.754 us; speedup vs baseline: 5.5921x; 1.0550x over previous
//
#include <hip/hip_runtime.h>
#include <hip/hip_bf16.h>
#include <math.h>

// B=4, NQ=300, NC=16, C=256, NH=8, NP=4, DFF=2048, H=W=128, Lq=4800, hd=32

typedef unsigned short u16;
typedef unsigned int u32;
typedef __attribute__((ext_vector_type(4))) float f32x4;
typedef __attribute__((ext_vector_type(8))) short s16x8;

__device__ __forceinline__ float b2f(u16 u) {
    union { u32 u; float f; } v; v.u = ((u32)u) << 16; return v.f;
}
__device__ __forceinline__ u16 f2b(float f) {
    union { float f; u32 u; } v; v.f = f;
    u32 r = v.u + 0x7fffu + ((v.u >> 16) & 1u);
    return (u16)(r >> 16);
}
__device__ __forceinline__ u32 pkbf(float a, float b) {
    u32 r;
    asm("v_cvt_pk_bf16_f32 %0, %1, %2" : "=v"(r) : "v"(a), "v"(b));
    return r;
}

// mean/var over 256 elements, block = 256 threads (4 waves)
__device__ __forceinline__ void block_meanvar(float v, float* sb, float& mean, float& rstd) {
    float s = v, s2 = v * v;
#pragma unroll
    for (int o = 32; o; o >>= 1) { s += __shfl_xor(s, o); s2 += __shfl_xor(s2, o); }
    int wv = threadIdx.x >> 6;
    if ((threadIdx.x & 63) == 0) { sb[wv] = s; sb[4 + wv] = s2; }
    __syncthreads();
    s  = sb[0] + sb[1] + sb[2] + sb[3];
    s2 = sb[4] + sb[5] + sb[6] + sb[7];
    mean = s * (1.f / 256.f);
    float var = s2 * (1.f / 256.f) - mean * mean;
    rstd = 1.f / sqrtf(var + 1e-5f);
    __syncthreads();
}

#define GLOAD_LDS16(g, l) \
    __builtin_amdgcn_global_load_lds((const __attribute__((address_space(1))) void*)(g), \
                                     (__attribute__((address_space(3))) void*)(l), 16, 0, 0)

// ---------------------------------------------------------------------------
// Fused fp32 -> bf16 conversion over up to 8 segments (all sizes % 8 == 0)
// ---------------------------------------------------------------------------
struct CvtSeg { const float* src; u16* dst; int nv; };  // nv = elems/8
struct Cvt8 { CvtSeg s[8]; };

__global__ __launch_bounds__(256) void cvt_multi(Cvt8 a, int totalv) {
    int v = blockIdx.x * 256 + threadIdx.x;
    if (v >= totalv) return;
    int si = 0;
    while (si < 7 && v >= a.s[si].nv) { v -= a.s[si].nv; ++si; }
    const float* src = a.s[si].src + (size_t)v * 8;
    u16* dst = a.s[si].dst + (size_t)v * 8;
    float4 x = *(const float4*)src;
    float4 y = *(const float4*)(src + 4);
    u16 u[8] = { f2b(x.x), f2b(x.y), f2b(x.z), f2b(x.w),
                 f2b(y.x), f2b(y.y), f2b(y.z), f2b(y.w) };
    *(uint4*)dst = *(const uint4*)u;
}

// pack off_w(64) + aw_w(32) + zeros(32) -> [128][256] bf16, bias -> [128] f32
__global__ __launch_bounds__(256) void pack_offaw(
    const float* __restrict__ off_w, const float* __restrict__ off_b,
    const float* __restrict__ aw_w, const float* __restrict__ aw_b,
    u16* __restrict__ wout, float* __restrict__ bout)
{
    int r = blockIdx.x, c = threadIdx.x;
    float v = 0.f;
    if (r < 64) v = off_w[r * 256 + c];
    else if (r < 96) v = aw_w[(r - 64) * 256 + c];
    wout[r * 256 + c] = f2b(v);
    if (c == 0) bout[r] = (r < 64) ? off_b[r] : (r < 96 ? aw_b[r - 64] : 0.f);
}

// ---------------------------------------------------------------------------
// MFMA bf16 GEMM: C[M,N] = A[M,K] @ W[N,K]^T + bias (128x128, BK=32)
// ---------------------------------------------------------------------------
template<int RELU, int OUTBF16>
__global__ __launch_bounds__(256) void gemm_mfma(
    const u16* __restrict__ A, const u16* __restrict__ W,
    const float* __restrict__ bias, void* __restrict__ Cout,
    int M, int N, int K)
{
    __shared__ u16 Asm[128 * 32];
    __shared__ u16 Bsm[128 * 32];
    const int tid = threadIdx.x;
    const int wave = tid >> 6, lane = tid & 63;
    const int bm = blockIdx.y * 128, bn = blockIdx.x * 128;
    const int wr = (wave >> 1) * 64, wc = (wave & 1) * 64;
    const int fr = lane & 15;
    const int fk = (lane >> 4) * 8;
    f32x4 acc[4][4] = {};

    for (int k0 = 0; k0 < K; k0 += 32) {
        __syncthreads();
#pragma unroll
        for (int c = 0; c < 2; ++c) {
            int chunk = wave + c * 4;
            int b = chunk * 1024 + lane * 16;
            int row = b >> 6;
            int ke = (b & 63) >> 1;
            int ra = bm + row; if (ra >= M) ra = M - 1;
            GLOAD_LDS16(A + (size_t)ra * K + k0 + ke, Asm + chunk * 512);
            int rb = bn + row;
            GLOAD_LDS16(W + (size_t)rb * K + k0 + ke, Bsm + chunk * 512);
        }
        __syncthreads();
        s16x8 af[4], bf[4];
#pragma unroll
        for (int i = 0; i < 4; ++i) {
            af[i] = *(const s16x8*)(Asm + (wr + i * 16 + fr) * 32 + fk);
            bf[i] = *(const s16x8*)(Bsm + (wc + i * 16 + fr) * 32 + fk);
        }
#pragma unroll
        for (int mi = 0; mi < 4; ++mi)
#pragma unroll
            for (int ni = 0; ni < 4; ++ni)
                acc[mi][ni] = __builtin_amdgcn_mfma_f32_16x16x32_bf16(
                    af[mi], bf[ni], acc[mi][ni], 0, 0, 0);
    }
    const int cc = lane & 15, cr4 = (lane >> 4) * 4;
#pragma unroll
    for (int mi = 0; mi < 4; ++mi) {
#pragma unroll
        for (int ni = 0; ni < 4; ++ni) {
            int col = bn + wc + ni * 16 + cc;
            float bv = bias[col];
#pragma unroll
            for (int j = 0; j < 4; ++j) {
                int row = bm + wr + mi * 16 + cr4 + j;
                if (row >= M) continue;
                float v = acc[mi][ni][j] + bv;
                if (RELU) v = fmaxf(v, 0.f);
                if (OUTBF16) ((u16*)Cout)[(size_t)row * N + col] = f2b(v);
                else ((float*)Cout)[(size_t)row * N + col] = v;
            }
        }
    }
}

// ---------------------------------------------------------------------------
// MFMA flash attention, swapped-operand (lane-local softmax).
// qkv[BI*300][768] bf16; block = (bi, h, seg); 4 waves, q-tiles of 16.
// S^T = mfma(K, Q): rows k (regs), cols q (lane&15). Per-lane online softmax.
// P re-layout to PV A-frag via 8 shfls (no LDS P buffer).
// ---------------------------------------------------------------------------
__global__ __launch_bounds__(256) void attn_mfma(
    const u16* __restrict__ qkv, u16* __restrict__ O, int S)
{
    const int bh = blockIdx.x / S, seg = blockIdx.x % S;
    const int bi = bh >> 3, h = bh & 7;
    __shared__ u16 Ks[320][40];    // K raw, row-major (80B stride, b128-aligned)
    __shared__ u16 Vt[32][328];    // V transposed [d][k] (656B stride)
    const int tid = threadIdx.x;

    // stage K (plain vector copy, no scaling)
    for (int idx = tid; idx < 1200; idx += 256) {
        int k = idx >> 2, sub = idx & 3;
        const u16* kp = qkv + ((size_t)(bi * 300 + k)) * 768 + 256 + h * 32 + sub * 8;
        *(uint4*)&Ks[k][sub * 8] = *(const uint4*)kp;
    }
    // stage V transposed: two k-rows per thread -> paired u32 writes
    for (int idx = tid; idx < 600; idx += 256) {
        int kp2 = idx >> 2, sub = idx & 3;
        int k0 = kp2 * 2;
        const u16* vp = qkv + ((size_t)(bi * 300 + k0)) * 768 + 512 + h * 32 + sub * 8;
        uint4 v0 = *(const uint4*)vp;
        uint4 v1 = *(const uint4*)(vp + 768);
        u16 a0[8], a1[8];
        *(uint4*)a0 = v0; *(uint4*)a1 = v1;
#pragma unroll
        for (int j = 0; j < 8; ++j)
            *(u32*)&Vt[sub * 8 + j][k0] = (u32)a0[j] | ((u32)a1[j] << 16);
    }
    // zero V tail k = 300..319 (PV reads them with p=0; avoid NaN*0)
    for (int idx = tid; idx < 320; idx += 256) {
        int d = idx & 31, kp2 = idx >> 5;
        *(u32*)&Vt[d][300 + kp2 * 2] = 0;
    }
    __syncthreads();

    const int lane = tid & 63, wave = tid >> 6;
    const int c = lane & 15, g = lane >> 4;
    const int fk = g * 8;
    const f32x4 zero = { 0.f, 0.f, 0.f, 0.f };
    const float SCL2 = 0.25505416f;           // (1/sqrt(32)) * log2(e)
    const int sA = c + ((g & 1) << 5);        // exchange source lanes
    const int sB = sA + 16;
    const bool hi = g >= 2;

    for (int qt = seg * 4 + wave; qt < 19; qt += 4 * S) {
        int qrow = qt * 16 + c; if (qrow > 299) qrow = 299;
        s16x8 afq = *(const s16x8*)(qkv + ((size_t)(bi * 300 + qrow)) * 768 + h * 32 + fk);
        f32x4 acc0 = zero, acc1 = zero;
        float m = -1e30f, l = 0.f;

        for (int kc = 0; kc < 10; ++kc) {
            const int kb = kc * 32;
            s16x8 ak0 = *(const s16x8*)&Ks[kb + c][fk];
            s16x8 ak1 = *(const s16x8*)&Ks[kb + 16 + c][fk];
            // S^T: rows k = kb + g*4 + j (ak0) / kb+16+g*4+j (ak1), col q = c
            f32x4 s0 = __builtin_amdgcn_mfma_f32_16x16x32_bf16(ak0, afq, zero, 0, 0, 0);
            f32x4 s1 = __builtin_amdgcn_mfma_f32_16x16x32_bf16(ak1, afq, zero, 0, 0, 0);
            if (kb == 288) {   // keys >= 300 invalid (overwrite kills any NaN)
#pragma unroll
                for (int j = 0; j < 4; ++j) {
                    if (g == 3) s0[j] = -1e30f;
                    s1[j] = -1e30f;
                }
            }
            // chunk max: 7 local + 2 shfl (lanes c, c+16, c+32, c+48 share q)
            float cm = fmaxf(fmaxf(fmaxf(s0[0], s0[1]), fmaxf(s0[2], s0[3])),
                             fmaxf(fmaxf(s1[0], s1[1]), fmaxf(s1[2], s1[3])));
            cm = fmaxf(cm, __shfl_xor(cm, 16));
            cm = fmaxf(cm, __shfl_xor(cm, 32));
            float mn = fmaxf(m, cm);
            float corr = exp2f((m - mn) * SCL2);
            m = mn;
            float p0[4], p1[4];
#pragma unroll
            for (int j = 0; j < 4; ++j) {
                p0[j] = exp2f((s0[j] - m) * SCL2);
                p1[j] = exp2f((s1[j] - m) * SCL2);
            }
            float cs = (p0[0] + p0[1]) + (p0[2] + p0[3])
                     + (p1[0] + p1[1]) + (p1[2] + p1[3]);
            cs += __shfl_xor(cs, 16);
            cs += __shfl_xor(cs, 32);
            l = l * corr + cs;
            // pack p -> bf16 pairs (consecutive k in each u32)
            u32 w0 = pkbf(p0[0], p0[1]), w1 = pkbf(p0[2], p0[3]);
            u32 w2 = pkbf(p1[0], p1[1]), w3 = pkbf(p1[2], p1[3]);
            // exchange: lane (c,g) needs P[q=c][k = kb+8g .. +7]
            int x0 = __shfl((int)w0, sA), x1 = __shfl((int)w1, sA);
            int x2 = __shfl((int)w2, sA), x3 = __shfl((int)w3, sA);
            int y0 = __shfl((int)w0, sB), y1 = __shfl((int)w1, sB);
            int y2 = __shfl((int)w2, sB), y3 = __shfl((int)w3, sB);
            union { u32 w[4]; s16x8 v; } afp;
            afp.w[0] = hi ? (u32)x2 : (u32)x0;
            afp.w[1] = hi ? (u32)x3 : (u32)x1;
            afp.w[2] = hi ? (u32)y2 : (u32)y0;
            afp.w[3] = hi ? (u32)y3 : (u32)y1;
            // rescale acc rows (row q = g*4+j; corr lives on lane q)
            float c0 = __shfl(corr, g * 4 + 0), c1 = __shfl(corr, g * 4 + 1);
            float c2 = __shfl(corr, g * 4 + 2), c3 = __shfl(corr, g * 4 + 3);
            acc0[0] *= c0; acc0[1] *= c1; acc0[2] *= c2; acc0[3] *= c3;
            acc1[0] *= c0; acc1[1] *= c1; acc1[2] *= c2; acc1[3] *= c3;
            s16x8 bv0 = *(const s16x8*)&Vt[c][kb + fk];
            s16x8 bv1 = *(const s16x8*)&Vt[16 + c][kb + fk];
            acc0 = __builtin_amdgcn_mfma_f32_16x16x32_bf16(afp.v, bv0, acc0, 0, 0, 0);
            acc1 = __builtin_amdgcn_mfma_f32_16x16x32_bf16(afp.v, bv1, acc1, 0, 0, 0);
        }
        // epilogue: rows q = g*4+j, cols d = c / 16+c
        float l0 = __shfl(l, g * 4 + 0), l1 = __shfl(l, g * 4 + 1);
        float l2 = __shfl(l, g * 4 + 2), l3 = __shfl(l, g * 4 + 3);
        float lj[4] = { l0, l1, l2, l3 };
#pragma unroll
        for (int j = 0; j < 4; ++j) {
            int q = qt * 16 + g * 4 + j;
            if (q < 300) {
                float r = 1.f / lj[j];
                u16* op = O + ((size_t)(bi * 300 + q)) * 256 + h * 32;
                op[c]      = f2b(acc0[j] * r);
                op[16 + c] = f2b(acc1[j] * r);
            }
        }
    }
}

// sc_x[(b*16+nc)*300+nq][c] = sub_contour_query[b][nq][nc][c]  (bf16 out)
__global__ __launch_bounds__(256) void sc_transpose(
    const float* __restrict__ scq, u16* __restrict__ out)
{
    int row = blockIdx.x;
    int b = row / 4800;
    int rem = row % 4800;
    int nc = rem / 300, nq = rem % 300;
    int c = threadIdx.x;
    out[(size_t)row * 256 + c] = f2b(scq[((size_t)((b * 300 + nq) * 16 + nc)) * 256 + c]);
}

// tgt = LN( scq + 2*(sc_o + inst_o) ) with n1; emits fp32 + bf16
__global__ __launch_bounds__(256) void ln1_combine(
    const float* __restrict__ scq, const float* __restrict__ sco,
    const float* __restrict__ insto, const float* __restrict__ g,
    const float* __restrict__ bta, float* __restrict__ tgt,
    u16* __restrict__ tgtb)
{
    __shared__ float sb[8];
    int row = blockIdx.x;
    int b = row / 4800;
    int rem = row % 4800;
    int nq = rem >> 4, nc = rem & 15;
    int c = threadIdx.x;
    float v = scq[(size_t)row * 256 + c]
            + 2.f * (sco[((size_t)((b * 16 + nc) * 300 + nq)) * 256 + c]
                   + insto[((size_t)(b * 300 + nq)) * 256 + c]);
    float mean, rstd;
    block_meanvar(v, sb, mean, rstd);
    float r = (v - mean) * rstd * g[c] + bta[c];
    tgt[(size_t)row * 256 + c] = r;
    tgtb[(size_t)row * 256 + c] = f2b(r);
}

// dst = LN(x + y); optional bf16 copy
__global__ __launch_bounds__(256) void ln_add(
    const float* __restrict__ x, const float* __restrict__ y,
    const float* __restrict__ g, const float* __restrict__ bta,
    float* __restrict__ dst, u16* __restrict__ bdst)
{
    __shared__ float sb[8];
    int row = blockIdx.x;
    int c = threadIdx.x;
    float v = x[(size_t)row * 256 + c] + y[(size_t)row * 256 + c];
    float mean, rstd;
    block_meanvar(v, sb, mean, rstd);
    float r = (v - mean) * rstd * g[c] + bta[c];
    dst[(size_t)row * 256 + c] = r;
    if (bdst) bdst[(size_t)row * 256 + c] = f2b(r);
}

// ---------------------------------------------------------------------------
// deformable bilinear sampling + aw-softmax reduce over NP=4 (bf16 out).
// H=W=128 hardcoded; branchless clamped addresses, 16 batched loads.
// ---------------------------------------------------------------------------
__global__ __launch_bounds__(256) void deform_sample(
    const float* __restrict__ oaw, const float* __restrict__ refb,
    const float* __restrict__ mem, u16* __restrict__ samp)
{
    const int row = blockIdx.x;
    const int b = row / 4800;
    const int tid = threadIdx.x;
    const int h = tid >> 5;
    const float4 rb = *(const float4*)(refb + (size_t)row * 4);
    const float* base = oaw + (size_t)row * 128;
    float a0 = base[64 + h * 4 + 0], a1 = base[64 + h * 4 + 1];
    float a2 = base[64 + h * 4 + 2], a3 = base[64 + h * 4 + 3];
    float am = fmaxf(fmaxf(a0, a1), fmaxf(a2, a3));
    float e0 = __expf(a0 - am), e1 = __expf(a1 - am), e2 = __expf(a2 - am), e3 = __expf(a3 - am);
    float rs = 1.f / (e0 + e1 + e2 + e3);
    float wp[4] = { e0 * rs, e1 * rs, e2 * rs, e3 * rs };
    const float* op = base + h * 8;
    const float* mb = mem + (size_t)b * 16384 * 256 + tid;

    int offs[16];
    float wts[16];
#pragma unroll
    for (int p = 0; p < 4; ++p) {
        float gx = (rb.x + op[p * 2 + 0] * rb.z * 0.5f) * 128.f - 0.5f;
        float gy = (rb.y + op[p * 2 + 1] * rb.w * 0.5f) * 128.f - 0.5f;
        float x0f = floorf(gx), y0f = floorf(gy);
        int x0 = (int)x0f, y0 = (int)y0f;
        float wx1 = gx - x0f, wy1 = gy - y0f;
        float wx0 = 1.f - wx1, wy0 = 1.f - wy1;
        float vx0 = ((unsigned)x0 < 128u) ? 1.f : 0.f;
        float vx1 = ((unsigned)(x0 + 1) < 128u) ? 1.f : 0.f;
        float vy0 = ((unsigned)y0 < 128u) ? 1.f : 0.f;
        float vy1 = ((unsigned)(y0 + 1) < 128u) ? 1.f : 0.f;
        int xc0 = min(max(x0, 0), 127), xc1 = min(max(x0 + 1, 0), 127);
        int yc0 = min(max(y0, 0), 127), yc1 = min(max(y0 + 1, 0), 127);
        offs[p * 4 + 0] = (yc0 * 128 + xc0) << 8;
        offs[p * 4 + 1] = (yc0 * 128 + xc1) << 8;
        offs[p * 4 + 2] = (yc1 * 128 + xc0) << 8;
        offs[p * 4 + 3] = (yc1 * 128 + xc1) << 8;
        wts[p * 4 + 0] = wp[p] * wx0 * wy0 * vx0 * vy0;
        wts[p * 4 + 1] = wp[p] * wx1 * wy0 * vx1 * vy0;
        wts[p * 4 + 2] = wp[p] * wx0 * wy1 * vx0 * vy1;
        wts[p * 4 + 3] = wp[p] * wx1 * wy1 * vx1 * vy1;
    }
    float vals[16];
#pragma unroll
    for (int i = 0; i < 16; ++i) vals[i] = mb[offs[i]];
    float acc = 0.f;
#pragma unroll
    for (int i = 0; i < 16; ++i) acc = fmaf(vals[i], wts[i], acc);
    samp[(size_t)row * 256 + tid] = f2b(acc);
}

extern "C" void kernel_launch(void* const* d_in, const int* in_sizes, int n_in,
                              void* d_out, int out_size, void* d_ws, size_t ws_size,
                              hipStream_t stream) {
    const float* inst_query = (const float*)d_in[0];
    const float* sub_contour = (const float*)d_in[1];
    const float* memory_feats = (const float*)d_in[2];
    const float* ref_boxes = (const float*)d_in[3];
    const float* inst_in_w = (const float*)d_in[4];
    const float* inst_in_b = (const float*)d_in[5];
    const float* inst_out_w = (const float*)d_in[6];
    const float* inst_out_b = (const float*)d_in[7];
    const float* sc_in_w = (const float*)d_in[8];
    const float* sc_in_b = (const float*)d_in[9];
    const float* sc_out_w = (const float*)d_in[10];
    const float* sc_out_b = (const float*)d_in[11];
    const float* off_w = (const float*)d_in[12];
    const float* off_b = (const float*)d_in[13];
    const float* aw_w = (const float*)d_in[14];
    const float* aw_b = (const float*)d_in[15];
    const float* outp_w = (const float*)d_in[16];
    const float* outp_b = (const float*)d_in[17];
    const float* lin1_w = (const float*)d_in[18];
    const float* lin1_b = (const float*)d_in[19];
    const float* lin2_w = (const float*)d_in[20];
    const float* lin2_b = (const float*)d_in[21];
    const float* n1_g = (const float*)d_in[22];
    const float* n1_b = (const float*)d_in[23];
    const float* n2_g = (const float*)d_in[24];
    const float* n2_b = (const float*)d_in[25];
    const float* n3_g = (const float*)d_in[26];
    const float* n3_b = (const float*)d_in[27];

    // ---- workspace layout ----
    u16* wsb = (u16*)d_ws;
    u16* qkv_b   = wsb;                       // 19200*768  = 14,745,600
    u16* xbuf_b  = qkv_b + 14745600;          //  4,915,200
    u16* obuf_b  = xbuf_b + 4915200;          //  4,915,200
    u16* tgt_b   = obuf_b + 4915200;          //  4,915,200
    u16* w_inst_in  = tgt_b + 4915200;        //    196,608
    u16* w_inst_out = w_inst_in + 196608;     //     65,536
    u16* w_sc_in    = w_inst_out + 65536;     //    196,608
    u16* w_sc_out   = w_sc_in + 196608;       //     65,536
    u16* w_outp     = w_sc_out + 65536;       //     65,536
    u16* w_lin1     = w_outp + 65536;         //    524,288
    u16* w_lin2     = w_lin1 + 524288;        //    524,288
    u16* w_offaw    = w_lin2 + 524288;        //     32,768
    u16* ffn1_b = qkv_b;                      // alias
    u16* instq_b = tgt_b;                     // temp (tgt_b not live yet)
    float* fp    = (float*)(w_offaw + 32768);
    float* insto = fp;                        //    307,200
    float* tgt   = insto + 307200;            //  4,915,200
    float* t2    = tgt + 4915200;             //  4,915,200
    float* oawb  = t2 + 4915200;              //  2,457,600
    float* b_offaw = oawb + 2457600;          //        128

    dim3 blk(256);

    // fused weight/activation conversions
    Cvt8 ca;
    ca.s[0] = { inst_in_w,  w_inst_in,  196608 / 8 };
    ca.s[1] = { inst_out_w, w_inst_out, 65536 / 8 };
    ca.s[2] = { sc_in_w,    w_sc_in,    196608 / 8 };
    ca.s[3] = { sc_out_w,   w_sc_out,   65536 / 8 };
    ca.s[4] = { outp_w,     w_outp,     65536 / 8 };
    ca.s[5] = { lin1_w,     w_lin1,     524288 / 8 };
    ca.s[6] = { lin2_w,     w_lin2,     524288 / 8 };
    ca.s[7] = { inst_query, instq_b,    307200 / 8 };
    int totalv = (196608 * 2 + 65536 * 3 + 524288 * 2 + 307200) / 8;
    cvt_multi<<<(totalv + 255) / 256, blk, 0, stream>>>(ca, totalv);
    pack_offaw<<<128, blk, 0, stream>>>(off_w, off_b, aw_w, aw_b, w_offaw, b_offaw);

    // 1. inst QKV -> qkv_b (bf16)
    gemm_mfma<0,1><<<dim3(6, 10), blk, 0, stream>>>(instq_b, w_inst_in, inst_in_b, qkv_b, 1200, 768, 256);
    // 2. inst attention
    attn_mfma<<<128, blk, 0, stream>>>(qkv_b, obuf_b, 4);
    // 3. inst out-proj -> insto (fp32)
    gemm_mfma<0,0><<<dim3(2, 10), blk, 0, stream>>>(obuf_b, w_inst_out, inst_out_b, insto, 1200, 256, 256);
    // 4. sc transpose -> xbuf_b (bf16)
    sc_transpose<<<19200, blk, 0, stream>>>(sub_contour, xbuf_b);
    // 5. sc QKV
    gemm_mfma<0,1><<<dim3(6, 150), blk, 0, stream>>>(xbuf_b, w_sc_in, sc_in_b, qkv_b, 19200, 768, 256);
    // 6. sc attention
    attn_mfma<<<1024, blk, 0, stream>>>(qkv_b, obuf_b, 2);
    // 7. sc out-proj -> t2 (fp32, sc row order)
    gemm_mfma<0,0><<<dim3(2, 150), blk, 0, stream>>>(obuf_b, w_sc_out, sc_out_b, t2, 19200, 256, 256);
    // 8. combine + LN1 -> tgt (fp32) + tgt_b (bf16)
    ln1_combine<<<19200, blk, 0, stream>>>(sub_contour, t2, insto, n1_g, n1_b, tgt, tgt_b);
    // 9. packed off+aw projection (MFMA) -> oawb [19200][128]
    gemm_mfma<0,0><<<dim3(1, 150), blk, 0, stream>>>(tgt_b, w_offaw, b_offaw, oawb, 19200, 128, 256);
    // 10. deformable sampling -> obuf_b (bf16)
    deform_sample<<<19200, blk, 0, stream>>>(oawb, ref_boxes, memory_feats, obuf_b);
    // 11. outp proj -> t2
    gemm_mfma<0,0><<<dim3(2, 150), blk, 0, stream>>>(obuf_b, w_outp, outp_b, t2, 19200, 256, 256);
    // 12. LN2 -> tgt (fp32) + tgt_b (bf16)
    ln_add<<<19200, blk, 0, stream>>>(tgt, t2, n2_g, n2_b, tgt, tgt_b);
    // 13. FFN in 2 chunks of 9600 rows (ffn1_b aliases dead qkv_b+xbuf_b)
    for (int c = 0; c < 2; ++c) {
        gemm_mfma<1,1><<<dim3(16, 75), blk, 0, stream>>>(tgt_b + (size_t)c * 9600 * 256, w_lin1, lin1_b, ffn1_b, 9600, 2048, 256);
        gemm_mfma<0,0><<<dim3(2, 75), blk, 0, stream>>>(ffn1_b, w_lin2, lin2_b, t2 + (size_t)c * 9600 * 256, 9600, 256, 2048);
    }
    // 14. LN3 -> output fp32 (B, NQ, NC, C)
    ln_add<<<19200, blk, 0, stream>>>(tgt, t2, n3_g, n3_b, (float*)d_out, nullptr);
}

// Round 6
// 380.692 us; speedup vs baseline: 6.1218x; 1.0947x over previous
//
#include <hip/hip_runtime.h>
#include <hip/hip_bf16.h>
#include <math.h>

// B=4, NQ=300, NC=16, C=256, NH=8, NP=4, DFF=2048, H=W=128, Lq=4800, hd=32

typedef unsigned short u16;
typedef unsigned int u32;
typedef __attribute__((ext_vector_type(4))) float f32x4;
typedef __attribute__((ext_vector_type(8))) short s16x8;

__device__ __forceinline__ float b2f(u16 u) {
    union { u32 u; float f; } v; v.u = ((u32)u) << 16; return v.f;
}
__device__ __forceinline__ u16 f2b(float f) {
    union { float f; u32 u; } v; v.f = f;
    u32 r = v.u + 0x7fffu + ((v.u >> 16) & 1u);
    return (u16)(r >> 16);
}
__device__ __forceinline__ u32 pkbf(float a, float b) {
    u32 r;
    asm("v_cvt_pk_bf16_f32 %0, %1, %2" : "=v"(r) : "v"(a), "v"(b));
    return r;
}

// mean/var over 256 elements, block = 256 threads (4 waves)
__device__ __forceinline__ void block_meanvar(float v, float* sb, float& mean, float& rstd) {
    float s = v, s2 = v * v;
#pragma unroll
    for (int o = 32; o; o >>= 1) { s += __shfl_xor(s, o); s2 += __shfl_xor(s2, o); }
    int wv = threadIdx.x >> 6;
    if ((threadIdx.x & 63) == 0) { sb[wv] = s; sb[4 + wv] = s2; }
    __syncthreads();
    s  = sb[0] + sb[1] + sb[2] + sb[3];
    s2 = sb[4] + sb[5] + sb[6] + sb[7];
    mean = s * (1.f / 256.f);
    float var = s2 * (1.f / 256.f) - mean * mean;
    rstd = 1.f / sqrtf(var + 1e-5f);
    __syncthreads();
}

#define GLOAD_LDS16(g, l) \
    __builtin_amdgcn_global_load_lds((const __attribute__((address_space(1))) void*)(g), \
                                     (__attribute__((address_space(3))) void*)(l), 16, 0, 0)

// ---------------------------------------------------------------------------
// Fused fp32 -> bf16 conversion over up to 8 segments (all sizes % 8 == 0)
// ---------------------------------------------------------------------------
struct CvtSeg { const float* src; u16* dst; int nv; };  // nv = elems/8
struct Cvt8 { CvtSeg s[8]; };

__global__ __launch_bounds__(256) void cvt_multi(Cvt8 a, int totalv) {
    int v = blockIdx.x * 256 + threadIdx.x;
    if (v >= totalv) return;
    int si = 0;
    while (si < 7 && v >= a.s[si].nv) { v -= a.s[si].nv; ++si; }
    const float* src = a.s[si].src + (size_t)v * 8;
    u16* dst = a.s[si].dst + (size_t)v * 8;
    float4 x = *(const float4*)src;
    float4 y = *(const float4*)(src + 4);
    u16 u[8] = { f2b(x.x), f2b(x.y), f2b(x.z), f2b(x.w),
                 f2b(y.x), f2b(y.y), f2b(y.z), f2b(y.w) };
    *(uint4*)dst = *(const uint4*)u;
}

// pack off_w(64) + aw_w(32) + zeros(32) -> [128][256] bf16, bias -> [128] f32
__global__ __launch_bounds__(256) void pack_offaw(
    const float* __restrict__ off_w, const float* __restrict__ off_b,
    const float* __restrict__ aw_w, const float* __restrict__ aw_b,
    u16* __restrict__ wout, float* __restrict__ bout)
{
    int r = blockIdx.x, c = threadIdx.x;
    float v = 0.f;
    if (r < 64) v = off_w[r * 256 + c];
    else if (r < 96) v = aw_w[(r - 64) * 256 + c];
    wout[r * 256 + c] = f2b(v);
    if (c == 0) bout[r] = (r < 64) ? off_b[r] : (r < 96 ? aw_b[r - 64] : 0.f);
}

// ---------------------------------------------------------------------------
// MFMA bf16 GEMM: C[M,N] = A[M,K] @ W[N,K]^T + bias (128x128, BK=32)
// ---------------------------------------------------------------------------
template<int RELU, int OUTBF16>
__global__ __launch_bounds__(256) void gemm_mfma(
    const u16* __restrict__ A, const u16* __restrict__ W,
    const float* __restrict__ bias, void* __restrict__ Cout,
    int M, int N, int K)
{
    __shared__ u16 Asm[128 * 32];
    __shared__ u16 Bsm[128 * 32];
    const int tid = threadIdx.x;
    const int wave = tid >> 6, lane = tid & 63;
    const int bm = blockIdx.y * 128, bn = blockIdx.x * 128;
    const int wr = (wave >> 1) * 64, wc = (wave & 1) * 64;
    const int fr = lane & 15;
    const int fk = (lane >> 4) * 8;
    f32x4 acc[4][4] = {};

    for (int k0 = 0; k0 < K; k0 += 32) {
        __syncthreads();
#pragma unroll
        for (int c = 0; c < 2; ++c) {
            int chunk = wave + c * 4;
            int b = chunk * 1024 + lane * 16;
            int row = b >> 6;
            int ke = (b & 63) >> 1;
            int ra = bm + row; if (ra >= M) ra = M - 1;
            GLOAD_LDS16(A + (size_t)ra * K + k0 + ke, Asm + chunk * 512);
            int rb = bn + row;
            GLOAD_LDS16(W + (size_t)rb * K + k0 + ke, Bsm + chunk * 512);
        }
        __syncthreads();
        s16x8 af[4], bf[4];
#pragma unroll
        for (int i = 0; i < 4; ++i) {
            af[i] = *(const s16x8*)(Asm + (wr + i * 16 + fr) * 32 + fk);
            bf[i] = *(const s16x8*)(Bsm + (wc + i * 16 + fr) * 32 + fk);
        }
#pragma unroll
        for (int mi = 0; mi < 4; ++mi)
#pragma unroll
            for (int ni = 0; ni < 4; ++ni)
                acc[mi][ni] = __builtin_amdgcn_mfma_f32_16x16x32_bf16(
                    af[mi], bf[ni], acc[mi][ni], 0, 0, 0);
    }
    const int cc = lane & 15, cr4 = (lane >> 4) * 4;
#pragma unroll
    for (int mi = 0; mi < 4; ++mi) {
#pragma unroll
        for (int ni = 0; ni < 4; ++ni) {
            int col = bn + wc + ni * 16 + cc;
            float bv = bias[col];
#pragma unroll
            for (int j = 0; j < 4; ++j) {
                int row = bm + wr + mi * 16 + cr4 + j;
                if (row >= M) continue;
                float v = acc[mi][ni][j] + bv;
                if (RELU) v = fmaxf(v, 0.f);
                if (OUTBF16) ((u16*)Cout)[(size_t)row * N + col] = f2b(v);
                else ((float*)Cout)[(size_t)row * N + col] = v;
            }
        }
    }
}

// ---------------------------------------------------------------------------
// MFMA flash attention, swapped-operand (lane-local softmax).
// Vt stored with 16B-chunk XOR swizzle: phys chunk = (k>>3) ^ (d&7); row
// stride 384 elems (768B, 48 chunks % 8 == 0) -> b128 reads hit each
// bank-quad exactly 8 times (the minimum). Rows c and c+16 swizzle equal.
// ---------------------------------------------------------------------------
#define VIDX(d, k) ((((k) >> 3) ^ ((d) & 7)) * 8 + ((k) & 7))

__global__ __launch_bounds__(256) void attn_mfma(
    const u16* __restrict__ qkv, u16* __restrict__ O, int S)
{
    const int bh = blockIdx.x / S, seg = blockIdx.x % S;
    const int bi = bh >> 3, h = bh & 7;
    __shared__ u16 Ks[320][40];    // K raw, row-major (80B stride: conflict-free)
    __shared__ u16 Vt[32][384];    // V transposed, XOR-swizzled chunks
    const int tid = threadIdx.x;

    // stage K (vector copy)
    for (int idx = tid; idx < 1200; idx += 256) {
        int k = idx >> 2, sub = idx & 3;
        const u16* kp = qkv + ((size_t)(bi * 300 + k)) * 768 + 256 + h * 32 + sub * 8;
        *(uint4*)&Ks[k][sub * 8] = *(const uint4*)kp;
    }
    // stage V transposed (swizzled): two k-rows per thread, paired u32 writes
    for (int idx = tid; idx < 600; idx += 256) {
        int kp2 = idx >> 2, sub = idx & 3;
        int k0 = kp2 * 2;
        const u16* vp = qkv + ((size_t)(bi * 300 + k0)) * 768 + 512 + h * 32 + sub * 8;
        uint4 v0 = *(const uint4*)vp;
        uint4 v1 = *(const uint4*)(vp + 768);
        u16 a0[8], a1[8];
        *(uint4*)a0 = v0; *(uint4*)a1 = v1;
#pragma unroll
        for (int j = 0; j < 8; ++j) {
            int d = sub * 8 + j;
            *(u32*)&Vt[d][VIDX(d, k0)] = (u32)a0[j] | ((u32)a1[j] << 16);
        }
    }
    // zero V tail k = 300..319 (PV reads them with p=0; avoid NaN*0)
    for (int idx = tid; idx < 320; idx += 256) {
        int d = idx & 31, k0 = 300 + (idx >> 5) * 2;
        *(u32*)&Vt[d][VIDX(d, k0)] = 0;
    }
    __syncthreads();

    const int lane = tid & 63, wave = tid >> 6;
    const int c = lane & 15, g = lane >> 4;
    const int fk = g * 8;
    const f32x4 zero = { 0.f, 0.f, 0.f, 0.f };
    const float SCL2 = 0.25505416f;           // (1/sqrt(32)) * log2(e)
    const int sA = c + ((g & 1) << 5);        // exchange source lanes
    const int sB = sA + 16;
    const bool hi = g >= 2;

    for (int qt = seg * 4 + wave; qt < 19; qt += 4 * S) {
        int qrow = qt * 16 + c; if (qrow > 299) qrow = 299;
        s16x8 afq = *(const s16x8*)(qkv + ((size_t)(bi * 300 + qrow)) * 768 + h * 32 + fk);
        f32x4 acc0 = zero, acc1 = zero;
        float m = -1e30f, l = 0.f;

        for (int kc = 0; kc < 10; ++kc) {
            const int kb = kc * 32;
            s16x8 ak0 = *(const s16x8*)&Ks[kb + c][fk];
            s16x8 ak1 = *(const s16x8*)&Ks[kb + 16 + c][fk];
            // S^T: rows k (regs), col q = c
            __builtin_amdgcn_s_setprio(1);
            f32x4 s0 = __builtin_amdgcn_mfma_f32_16x16x32_bf16(ak0, afq, zero, 0, 0, 0);
            f32x4 s1 = __builtin_amdgcn_mfma_f32_16x16x32_bf16(ak1, afq, zero, 0, 0, 0);
            __builtin_amdgcn_s_setprio(0);
            if (kb == 288) {   // keys >= 300 invalid (overwrite kills any NaN)
#pragma unroll
                for (int j = 0; j < 4; ++j) {
                    if (g == 3) s0[j] = -1e30f;
                    s1[j] = -1e30f;
                }
            }
            // chunk max: 7 local + 2 shfl
            float cm = fmaxf(fmaxf(fmaxf(s0[0], s0[1]), fmaxf(s0[2], s0[3])),
                             fmaxf(fmaxf(s1[0], s1[1]), fmaxf(s1[2], s1[3])));
            cm = fmaxf(cm, __shfl_xor(cm, 16));
            cm = fmaxf(cm, __shfl_xor(cm, 32));
            float mn = fmaxf(m, cm);
            float corr = exp2f((m - mn) * SCL2);
            m = mn;
            float p0[4], p1[4];
#pragma unroll
            for (int j = 0; j < 4; ++j) {
                p0[j] = exp2f((s0[j] - m) * SCL2);
                p1[j] = exp2f((s1[j] - m) * SCL2);
            }
            float cs = (p0[0] + p0[1]) + (p0[2] + p0[3])
                     + (p1[0] + p1[1]) + (p1[2] + p1[3]);
            cs += __shfl_xor(cs, 16);
            cs += __shfl_xor(cs, 32);
            l = l * corr + cs;
            // pack p -> bf16 pairs, exchange to PV A-frag via 8 shfls
            u32 w0 = pkbf(p0[0], p0[1]), w1 = pkbf(p0[2], p0[3]);
            u32 w2 = pkbf(p1[0], p1[1]), w3 = pkbf(p1[2], p1[3]);
            int x0 = __shfl((int)w0, sA), x1 = __shfl((int)w1, sA);
            int x2 = __shfl((int)w2, sA), x3 = __shfl((int)w3, sA);
            int y0 = __shfl((int)w0, sB), y1 = __shfl((int)w1, sB);
            int y2 = __shfl((int)w2, sB), y3 = __shfl((int)w3, sB);
            union { u32 w[4]; s16x8 v; } afp;
            afp.w[0] = hi ? (u32)x2 : (u32)x0;
            afp.w[1] = hi ? (u32)x3 : (u32)x1;
            afp.w[2] = hi ? (u32)y2 : (u32)y0;
            afp.w[3] = hi ? (u32)y3 : (u32)y1;
            // rescale acc rows (corr lives on lane q)
            float c0 = __shfl(corr, g * 4 + 0), c1 = __shfl(corr, g * 4 + 1);
            float c2 = __shfl(corr, g * 4 + 2), c3 = __shfl(corr, g * 4 + 3);
            acc0[0] *= c0; acc0[1] *= c1; acc0[2] *= c2; acc0[3] *= c3;
            acc1[0] *= c0; acc1[1] *= c1; acc1[2] *= c2; acc1[3] *= c3;
            s16x8 bv0 = *(const s16x8*)&Vt[c][VIDX(c, kb + fk)];
            s16x8 bv1 = *(const s16x8*)&Vt[16 + c][VIDX(16 + c, kb + fk)];
            __builtin_amdgcn_s_setprio(1);
            acc0 = __builtin_amdgcn_mfma_f32_16x16x32_bf16(afp.v, bv0, acc0, 0, 0, 0);
            acc1 = __builtin_amdgcn_mfma_f32_16x16x32_bf16(afp.v, bv1, acc1, 0, 0, 0);
            __builtin_amdgcn_s_setprio(0);
        }
        // epilogue: rows q = g*4+j, cols d = c / 16+c
        float l0 = __shfl(l, g * 4 + 0), l1 = __shfl(l, g * 4 + 1);
        float l2 = __shfl(l, g * 4 + 2), l3 = __shfl(l, g * 4 + 3);
        float lj[4] = { l0, l1, l2, l3 };
#pragma unroll
        for (int j = 0; j < 4; ++j) {
            int q = qt * 16 + g * 4 + j;
            if (q < 300) {
                float r = 1.f / lj[j];
                u16* op = O + ((size_t)(bi * 300 + q)) * 256 + h * 32;
                op[c]      = f2b(acc0[j] * r);
                op[16 + c] = f2b(acc1[j] * r);
            }
        }
    }
}

// sc_x[(b*16+nc)*300+nq][c] = sub_contour_query[b][nq][nc][c]  (bf16 out)
__global__ __launch_bounds__(256) void sc_transpose(
    const float* __restrict__ scq, u16* __restrict__ out)
{
    int row = blockIdx.x;
    int b = row / 4800;
    int rem = row % 4800;
    int nc = rem / 300, nq = rem % 300;
    int c = threadIdx.x;
    out[(size_t)row * 256 + c] = f2b(scq[((size_t)((b * 300 + nq) * 16 + nc)) * 256 + c]);
}

// tgt = LN( scq + 2*(sc_o + inst_o) ) with n1; emits fp32 + bf16
__global__ __launch_bounds__(256) void ln1_combine(
    const float* __restrict__ scq, const float* __restrict__ sco,
    const float* __restrict__ insto, const float* __restrict__ g,
    const float* __restrict__ bta, float* __restrict__ tgt,
    u16* __restrict__ tgtb)
{
    __shared__ float sb[8];
    int row = blockIdx.x;
    int b = row / 4800;
    int rem = row % 4800;
    int nq = rem >> 4, nc = rem & 15;
    int c = threadIdx.x;
    float v = scq[(size_t)row * 256 + c]
            + 2.f * (sco[((size_t)((b * 16 + nc) * 300 + nq)) * 256 + c]
                   + insto[((size_t)(b * 300 + nq)) * 256 + c]);
    float mean, rstd;
    block_meanvar(v, sb, mean, rstd);
    float r = (v - mean) * rstd * g[c] + bta[c];
    tgt[(size_t)row * 256 + c] = r;
    tgtb[(size_t)row * 256 + c] = f2b(r);
}

// dst = LN(x + y); optional bf16 copy
__global__ __launch_bounds__(256) void ln_add(
    const float* __restrict__ x, const float* __restrict__ y,
    const float* __restrict__ g, const float* __restrict__ bta,
    float* __restrict__ dst, u16* __restrict__ bdst)
{
    __shared__ float sb[8];
    int row = blockIdx.x;
    int c = threadIdx.x;
    float v = x[(size_t)row * 256 + c] + y[(size_t)row * 256 + c];
    float mean, rstd;
    block_meanvar(v, sb, mean, rstd);
    float r = (v - mean) * rstd * g[c] + bta[c];
    dst[(size_t)row * 256 + c] = r;
    if (bdst) bdst[(size_t)row * 256 + c] = f2b(r);
}

// ---------------------------------------------------------------------------
// deformable bilinear sampling + aw-softmax reduce over NP=4 (bf16 out).
// H=W=128 hardcoded; branchless clamped addresses, 16 batched loads.
// ---------------------------------------------------------------------------
__global__ __launch_bounds__(256) void deform_sample(
    const float* __restrict__ oaw, const float* __restrict__ refb,
    const float* __restrict__ mem, u16* __restrict__ samp)
{
    const int row = blockIdx.x;
    const int b = row / 4800;
    const int tid = threadIdx.x;
    const int h = tid >> 5;
    const float4 rb = *(const float4*)(refb + (size_t)row * 4);
    const float* base = oaw + (size_t)row * 128;
    float a0 = base[64 + h * 4 + 0], a1 = base[64 + h * 4 + 1];
    float a2 = base[64 + h * 4 + 2], a3 = base[64 + h * 4 + 3];
    float am = fmaxf(fmaxf(a0, a1), fmaxf(a2, a3));
    float e0 = __expf(a0 - am), e1 = __expf(a1 - am), e2 = __expf(a2 - am), e3 = __expf(a3 - am);
    float rs = 1.f / (e0 + e1 + e2 + e3);
    float wp[4] = { e0 * rs, e1 * rs, e2 * rs, e3 * rs };
    const float* op = base + h * 8;
    const float* mb = mem + (size_t)b * 16384 * 256 + tid;

    int offs[16];
    float wts[16];
#pragma unroll
    for (int p = 0; p < 4; ++p) {
        float gx = (rb.x + op[p * 2 + 0] * rb.z * 0.5f) * 128.f - 0.5f;
        float gy = (rb.y + op[p * 2 + 1] * rb.w * 0.5f) * 128.f - 0.5f;
        float x0f = floorf(gx), y0f = floorf(gy);
        int x0 = (int)x0f, y0 = (int)y0f;
        float wx1 = gx - x0f, wy1 = gy - y0f;
        float wx0 = 1.f - wx1, wy0 = 1.f - wy1;
        float vx0 = ((unsigned)x0 < 128u) ? 1.f : 0.f;
        float vx1 = ((unsigned)(x0 + 1) < 128u) ? 1.f : 0.f;
        float vy0 = ((unsigned)y0 < 128u) ? 1.f : 0.f;
        float vy1 = ((unsigned)(y0 + 1) < 128u) ? 1.f : 0.f;
        int xc0 = min(max(x0, 0), 127), xc1 = min(max(x0 + 1, 0), 127);
        int yc0 = min(max(y0, 0), 127), yc1 = min(max(y0 + 1, 0), 127);
        offs[p * 4 + 0] = (yc0 * 128 + xc0) << 8;
        offs[p * 4 + 1] = (yc0 * 128 + xc1) << 8;
        offs[p * 4 + 2] = (yc1 * 128 + xc0) << 8;
        offs[p * 4 + 3] = (yc1 * 128 + xc1) << 8;
        wts[p * 4 + 0] = wp[p] * wx0 * wy0 * vx0 * vy0;
        wts[p * 4 + 1] = wp[p] * wx1 * wy0 * vx1 * vy0;
        wts[p * 4 + 2] = wp[p] * wx0 * wy1 * vx0 * vy1;
        wts[p * 4 + 3] = wp[p] * wx1 * wy1 * vx1 * vy1;
    }
    float vals[16];
#pragma unroll
    for (int i = 0; i < 16; ++i) vals[i] = mb[offs[i]];
    float acc = 0.f;
#pragma unroll
    for (int i = 0; i < 16; ++i) acc = fmaf(vals[i], wts[i], acc);
    samp[(size_t)row * 256 + tid] = f2b(acc);
}

extern "C" void kernel_launch(void* const* d_in, const int* in_sizes, int n_in,
                              void* d_out, int out_size, void* d_ws, size_t ws_size,
                              hipStream_t stream) {
    const float* inst_query = (const float*)d_in[0];
    const float* sub_contour = (const float*)d_in[1];
    const float* memory_feats = (const float*)d_in[2];
    const float* ref_boxes = (const float*)d_in[3];
    const float* inst_in_w = (const float*)d_in[4];
    const float* inst_in_b = (const float*)d_in[5];
    const float* inst_out_w = (const float*)d_in[6];
    const float* inst_out_b = (const float*)d_in[7];
    const float* sc_in_w = (const float*)d_in[8];
    const float* sc_in_b = (const float*)d_in[9];
    const float* sc_out_w = (const float*)d_in[10];
    const float* sc_out_b = (const float*)d_in[11];
    const float* off_w = (const float*)d_in[12];
    const float* off_b = (const float*)d_in[13];
    const float* aw_w = (const float*)d_in[14];
    const float* aw_b = (const float*)d_in[15];
    const float* outp_w = (const float*)d_in[16];
    const float* outp_b = (const float*)d_in[17];
    const float* lin1_w = (const float*)d_in[18];
    const float* lin1_b = (const float*)d_in[19];
    const float* lin2_w = (const float*)d_in[20];
    const float* lin2_b = (const float*)d_in[21];
    const float* n1_g = (const float*)d_in[22];
    const float* n1_b = (const float*)d_in[23];
    const float* n2_g = (const float*)d_in[24];
    const float* n2_b = (const float*)d_in[25];
    const float* n3_g = (const float*)d_in[26];
    const float* n3_b = (const float*)d_in[27];

    // ---- workspace layout ----
    u16* wsb = (u16*)d_ws;
    u16* qkv_b   = wsb;                       // 19200*768  = 14,745,600
    u16* xbuf_b  = qkv_b + 14745600;          //  4,915,200
    u16* obuf_b  = xbuf_b + 4915200;          //  4,915,200
    u16* tgt_b   = obuf_b + 4915200;          //  4,915,200
    u16* w_inst_in  = tgt_b + 4915200;        //    196,608
    u16* w_inst_out = w_inst_in + 196608;     //     65,536
    u16* w_sc_in    = w_inst_out + 65536;     //    196,608
    u16* w_sc_out   = w_sc_in + 196608;       //     65,536
    u16* w_outp     = w_sc_out + 65536;       //     65,536
    u16* w_lin1     = w_outp + 65536;         //    524,288
    u16* w_lin2     = w_lin1 + 524288;        //    524,288
    u16* w_offaw    = w_lin2 + 524288;        //     32,768
    u16* ffn1_b = qkv_b;                      // alias (2-chunk path)
    u16* instq_b = tgt_b;                     // temp (tgt_b not live yet)
    float* fp    = (float*)(w_offaw + 32768);
    float* insto = fp;                        //    307,200
    float* tgt   = insto + 307200;            //  4,915,200
    float* t2    = tgt + 4915200;             //  4,915,200
    float* oawb  = t2 + 4915200;              //  2,457,600
    float* b_offaw = oawb + 2457600;          //        128
    // full-FFN scratch (if workspace allows): 19200*2048 bf16 after base
    size_t base_bytes = (size_t)((char*)(b_offaw + 128) - (char*)d_ws);
    size_t ffn_off = (base_bytes + 255) & ~(size_t)255;
    u16* ffn1_full = (u16*)((char*)d_ws + ffn_off);
    bool full_ffn = ws_size >= ffn_off + (size_t)2 * 19200 * 2048;

    dim3 blk(256);

    // fused weight/activation conversions
    Cvt8 ca;
    ca.s[0] = { inst_in_w,  w_inst_in,  196608 / 8 };
    ca.s[1] = { inst_out_w, w_inst_out, 65536 / 8 };
    ca.s[2] = { sc_in_w,    w_sc_in,    196608 / 8 };
    ca.s[3] = { sc_out_w,   w_sc_out,   65536 / 8 };
    ca.s[4] = { outp_w,     w_outp,     65536 / 8 };
    ca.s[5] = { lin1_w,     w_lin1,     524288 / 8 };
    ca.s[6] = { lin2_w,     w_lin2,     524288 / 8 };
    ca.s[7] = { inst_query, instq_b,    307200 / 8 };
    int totalv = (196608 * 2 + 65536 * 3 + 524288 * 2 + 307200) / 8;
    cvt_multi<<<(totalv + 255) / 256, blk, 0, stream>>>(ca, totalv);
    pack_offaw<<<128, blk, 0, stream>>>(off_w, off_b, aw_w, aw_b, w_offaw, b_offaw);

    // 1. inst QKV -> qkv_b (bf16)
    gemm_mfma<0,1><<<dim3(6, 10), blk, 0, stream>>>(instq_b, w_inst_in, inst_in_b, qkv_b, 1200, 768, 256);
    // 2. inst attention
    attn_mfma<<<128, blk, 0, stream>>>(qkv_b, obuf_b, 4);
    // 3. inst out-proj -> insto (fp32)
    gemm_mfma<0,0><<<dim3(2, 10), blk, 0, stream>>>(obuf_b, w_inst_out, inst_out_b, insto, 1200, 256, 256);
    // 4. sc transpose -> xbuf_b (bf16)
    sc_transpose<<<19200, blk, 0, stream>>>(sub_contour, xbuf_b);
    // 5. sc QKV
    gemm_mfma<0,1><<<dim3(6, 150), blk, 0, stream>>>(xbuf_b, w_sc_in, sc_in_b, qkv_b, 19200, 768, 256);
    // 6. sc attention
    attn_mfma<<<1024, blk, 0, stream>>>(qkv_b, obuf_b, 2);
    // 7. sc out-proj -> t2 (fp32, sc row order)
    gemm_mfma<0,0><<<dim3(2, 150), blk, 0, stream>>>(obuf_b, w_sc_out, sc_out_b, t2, 19200, 256, 256);
    // 8. combine + LN1 -> tgt (fp32) + tgt_b (bf16)
    ln1_combine<<<19200, blk, 0, stream>>>(sub_contour, t2, insto, n1_g, n1_b, tgt, tgt_b);
    // 9. packed off+aw projection (MFMA) -> oawb [19200][128]
    gemm_mfma<0,0><<<dim3(1, 150), blk, 0, stream>>>(tgt_b, w_offaw, b_offaw, oawb, 19200, 128, 256);
    // 10. deformable sampling -> obuf_b (bf16)
    deform_sample<<<19200, blk, 0, stream>>>(oawb, ref_boxes, memory_feats, obuf_b);
    // 11. outp proj -> t2
    gemm_mfma<0,0><<<dim3(2, 150), blk, 0, stream>>>(obuf_b, w_outp, outp_b, t2, 19200, 256, 256);
    // 12. LN2 -> tgt (fp32) + tgt_b (bf16)
    ln_add<<<19200, blk, 0, stream>>>(tgt, t2, n2_g, n2_b, tgt, tgt_b);
    // 13. FFN: single dispatch if scratch fits (300-block lin2 keeps CUs busy),
    //     else 2 chunks of 9600 rows aliasing dead qkv_b/xbuf_b.
    if (full_ffn) {
        gemm_mfma<1,1><<<dim3(16, 150), blk, 0, stream>>>(tgt_b, w_lin1, lin1_b, ffn1_full, 19200, 2048, 256);
        gemm_mfma<0,0><<<dim3(2, 150), blk, 0, stream>>>(ffn1_full, w_lin2, lin2_b, t2, 19200, 256, 2048);
    } else {
        for (int c = 0; c < 2; ++c) {
            gemm_mfma<1,1><<<dim3(16, 75), blk, 0, stream>>>(tgt_b + (size_t)c * 9600 * 256, w_lin1, lin1_b, ffn1_b, 9600, 2048, 256);
            gemm_mfma<0,0><<<dim3(2, 75), blk, 0, stream>>>(ffn1_b, w_lin2, lin2_b, t2 + (size_t)c * 9600 * 256, 9600, 256, 2048);
        }
    }
    // 14. LN3 -> output fp32 (B, NQ, NC, C)
    ln_add<<<19200, blk, 0, stream>>>(tgt, t2, n3_g, n3_b, (float*)d_out, nullptr);
}